// Round 6
// baseline (847.380 us; speedup 1.0000x reference)
//
#include <hip/hip_runtime.h>
#include <hip/hip_bf16.h>
#include <cstddef>

// B=4, C=32, H=W=512. NHWC bf16 MFMA pipeline.
// Key identity: conv1(160->32) o operator == single 5x5 conv on x with
// composed weights K5[oc][ic] = sum_br istd_br * (W1[oc][br*32+ic] (*) S_br),
// exact for outputs >=1px from the border (reflect-101 staged x); the 1px
// border (conv1 zero-pad semantics) is fixed by k_border overwriting the
// perimeter pooled cells.

typedef unsigned short u16;
typedef unsigned int uint;
typedef __attribute__((ext_vector_type(8))) short short8v;
typedef __attribute__((ext_vector_type(4))) float float4v;

constexpr int Bn = 4, Cn = 32, Hn = 512, Wn = 512;
constexpr int PLANE = Hn * Wn;

__device__ __forceinline__ float b2f(u16 u) {
  union { uint i; float f; } c; c.i = ((uint)u) << 16; return c.f;
}
__device__ __forceinline__ u16 f2b(float f) {
  union { float f; uint i; } c; c.f = f;
  uint r = c.i + 0x7FFFu + ((c.i >> 16) & 1u);
  return (u16)(r >> 16);
}

static __device__ __forceinline__ int reflect_idx(int i, int n) {
  return i < 0 ? -i : (i >= n ? 2 * n - 2 - i : i);
}

// Combined stencils (0.5*(Kx+Ky) folded); validated rounds 3-5.
#define BRANCH_VALS(n00, n01, n02, n10, n11, n12, n20, n21, n22, v1, v2, v3, v4, v5)        \
  do {                                                                                      \
    v1 = -(n00 + n01 + n10) + (n12 + n21 + n22);                                            \
    v2 = -3.f * n00 - 5.f * n01 - 5.f * n10 + 5.f * n12 + 5.f * n21 + 3.f * n22;            \
    v3 = 2.f * (n00 + n02 + n20 + n22) - 8.f * n11;                                         \
    v4 = 0.5f * (-n00 - n01 + n10 + n11);                                                   \
    v5 = 0.5f * n01 + n02 - 0.5f * n10 + 0.5f * n12 - n20 - 0.5f * n21;                     \
  } while (0)

// Stencil taps S_br[s*3+t]: B[p] = sum S[s][t] x[p+(s-1,t-1)]
__device__ const float Sdev[5][9] = {
    {-1.f, -1.f, 0.f, -1.f, 0.f, 1.f, 0.f, 1.f, 1.f},
    {-3.f, -5.f, 0.f, -5.f, 0.f, 5.f, 0.f, 5.f, 3.f},
    {2.f, 0.f, 2.f, 0.f, -8.f, 0.f, 2.f, 0.f, 2.f},
    {-0.5f, -0.5f, 0.f, 0.5f, 0.5f, 0.f, 0.f, 0.f, 0.f},
    {0.f, 0.5f, 1.f, -0.5f, 0.f, 0.5f, -1.f, -0.5f, 0.f}};

// ---------------------------------------------------------------------------
// Stats pass over x (all samples): per-(b,br) partial (sum, sumsq). Validated.
// ---------------------------------------------------------------------------
__global__ void __launch_bounds__(128) k_opstats(const float* __restrict__ x,
                                                 float* __restrict__ partS,
                                                 float* __restrict__ partQ) {
  int bid = blockIdx.x;  // 8192
  int b = bid >> 11;
  int local = bid & 2047;
  int c = local >> 6;
  int chunk = local & 63;
  int t = threadIdx.x;
  int w0 = t * 4;
  const float* xp = x + (size_t)(b * Cn + c) * PLANE;
  int h0 = chunk * 8;

  int ci[6];
#pragma unroll
  for (int j = 0; j < 6; j++) ci[j] = reflect_idx(w0 - 1 + j, Wn);

  float ap[6], ac[6], an[6];
  {
    const float* rp = xp + reflect_idx(h0 - 1, Hn) * Wn;
#pragma unroll
    for (int j = 0; j < 6; j++) ap[j] = rp[ci[j]];
  }
  {
    const float* rp = xp + h0 * Wn;
#pragma unroll
    for (int j = 0; j < 6; j++) ac[j] = rp[ci[j]];
  }

  float s[5] = {0, 0, 0, 0, 0}, q[5] = {0, 0, 0, 0, 0};
#pragma unroll
  for (int r = 0; r < 8; ++r) {
    int h = h0 + r;
    const float* rp = xp + reflect_idx(h + 1, Hn) * Wn;
#pragma unroll
    for (int j = 0; j < 6; j++) an[j] = rp[ci[j]];
#pragma unroll
    for (int k = 0; k < 4; ++k) {
      float v1, v2, v3, v4, v5;
      BRANCH_VALS(ap[k], ap[k + 1], ap[k + 2], ac[k], ac[k + 1], ac[k + 2],
                  an[k], an[k + 1], an[k + 2], v1, v2, v3, v4, v5);
      s[0] += v1; q[0] += v1 * v1;
      s[1] += v2; q[1] += v2 * v2;
      s[2] += v3; q[2] += v3 * v3;
      s[3] += v4; q[3] += v4 * v4;
      s[4] += v5; q[4] += v5 * v5;
    }
#pragma unroll
    for (int j = 0; j < 6; j++) { ap[j] = ac[j]; ac[j] = an[j]; }
  }

#pragma unroll
  for (int i = 0; i < 5; i++) {
    float ss = s[i], qq = q[i];
#pragma unroll
    for (int off = 32; off > 0; off >>= 1) {
      ss += __shfl_down(ss, off);
      qq += __shfl_down(qq, off);
    }
    if ((t & 63) == 0) {
      int wv = t >> 6;
      int g = b * 5 + i;
      int idx = (c * 64 + chunk) * 2 + wv;
      partS[(size_t)g * 4096 + idx] = ss;
      partQ[(size_t)g * 4096 + idx] = qq;
    }
  }
}

__global__ void __launch_bounds__(256) k_stats(const float* __restrict__ partS,
                                               const float* __restrict__ partQ,
                                               float* __restrict__ stats) {
  __shared__ float red[256];
  int g = blockIdx.x;  // 20
  int t = threadIdx.x;
  float ss = 0.f, qq = 0.f;
  const float* ps = partS + (size_t)g * 4096;
  const float* pq = partQ + (size_t)g * 4096;
  for (int i = t; i < 4096; i += 256) {
    ss += ps[i];
    qq += pq[i];
  }
  red[t] = ss;
  __syncthreads();
  for (int o = 128; o > 0; o >>= 1) {
    if (t < o) red[t] += red[t + o];
    __syncthreads();
  }
  float S = red[0];
  __syncthreads();
  red[t] = qq;
  __syncthreads();
  for (int o = 128; o > 0; o >>= 1) {
    if (t < o) red[t] += red[t + o];
    __syncthreads();
  }
  if (t == 0) {
    const float N = 8388608.0f;
    float mean = S / N;
    float var = red[0] / N - mean * mean;
    stats[g * 2] = mean;
    stats[g * 2 + 1] = 1.0f / sqrtf(var);
  }
}

// ---------------------------------------------------------------------------
// Shared weight prep: conv2..7 -> A[tap][oc][ic]; deconv -> Adc[par][oc][ic].
// ---------------------------------------------------------------------------
__global__ void __launch_bounds__(256) k_prep_shared(
    const float* w2, const float* w3, const float* w4, const float* w5,
    const float* w6, const float* w7, const float* dw1, const float* dw2,
    const float* dw3, u16* A2, u16* A3, u16* A4, u16* A5, u16* A6, u16* A7,
    u16* Ad1, u16* Ad2, u16* Ad3) {
  int id = blockIdx.x * 256 + threadIdx.x;
  if (id < 55296) {
    int s = id / 9216, r = id % 9216;
    int tap = r / 1024, oc = (r >> 5) & 31, ic = r & 31;
    const float* w = s == 0 ? w2 : s == 1 ? w3 : s == 2 ? w4 : s == 3 ? w5 : s == 4 ? w6 : w7;
    u16* A = s == 0 ? A2 : s == 1 ? A3 : s == 2 ? A4 : s == 3 ? A5 : s == 4 ? A6 : A7;
    A[r] = f2b(w[(oc * 32 + ic) * 9 + tap]);
  } else if (id < 67584) {
    int r = id - 55296;
    int s = r / 4096, e = r % 4096;
    int par = e >> 10, oc = (e >> 5) & 31, ic = e & 31;
    const float* w = s == 0 ? dw1 : s == 1 ? dw2 : dw3;
    u16* A = s == 0 ? Ad1 : s == 1 ? Ad2 : Ad3;
    A[e] = f2b(w[(ic * 32 + oc) * 4 + par]);
  }
}

// ---------------------------------------------------------------------------
// Composed conv1 prep (per sample): A5c[b][tap25][oc][ic] bf16 with
// K5[u,v] = sum_br istd * sum_{a+s=u, bb+t=v} W1[a,bb] * S_br[s,t];
// bias1all[b][oc] = b1[oc] - sum_ch mean*istd*sum_taps W1.
// ---------------------------------------------------------------------------
__global__ void __launch_bounds__(256) k_prep_conv1(const float* __restrict__ w1,
                                                    const float* __restrict__ b1,
                                                    const float* __restrict__ stats,
                                                    u16* __restrict__ A5c,
                                                    float* __restrict__ bias1all) {
  int e = blockIdx.x * 256 + threadIdx.x;
  if (e < 102400) {
    int b = e / 25600, r = e % 25600;
    int tap = r >> 10, oc = (r >> 5) & 31, ic = r & 31;
    int u = tap / 5, v = tap % 5;
    float acc = 0.f;
#pragma unroll
    for (int br = 0; br < 5; ++br) {
      float is = stats[(b * 5 + br) * 2 + 1];
      const float* wp = w1 + ((size_t)oc * 160 + br * 32 + ic) * 9;
      float sub = 0.f;
#pragma unroll
      for (int a = 0; a < 3; ++a) {
        int s = u - a;
        if (s < 0 || s > 2) continue;
#pragma unroll
        for (int bb = 0; bb < 3; ++bb) {
          int tt = v - bb;
          if (tt < 0 || tt > 2) continue;
          sub += wp[a * 3 + bb] * Sdev[br][s * 3 + tt];
        }
      }
      acc += is * sub;
    }
    A5c[e] = f2b(acc);
  } else if (e < 102528) {
    int t2 = e - 102400;
    int b = t2 >> 5, oc = t2 & 31;
    float s = 0.f;
    for (int ch = 0; ch < 160; ++ch) {
      int br = ch >> 5;
      float mi = stats[(b * 5 + br) * 2] * stats[(b * 5 + br) * 2 + 1];
      const float* wp = w1 + (size_t)(oc * 160 + ch) * 9;
      float ws = 0.f;
#pragma unroll
      for (int tap = 0; tap < 9; ++tap) ws += wp[tap];
      s += ws * mi;
    }
    bias1all[b * 32 + oc] = b1[oc] - s;
  }
}

// ---------------------------------------------------------------------------
// Fused operator+conv1+pool: 5x5 MFMA conv on x (NCHW fp32, reflect-101
// staged to bf16 LDS), composed weights, fused 2x2 maxpool -> p1 NHWC bf16.
// Grid (32,32,4). Interior-exact; 1px border fixed by k_border afterwards.
// ---------------------------------------------------------------------------
__global__ void __launch_bounds__(256) k_conv5x5(const float* __restrict__ x,
                                                 const u16* __restrict__ A5c,
                                                 const float* __restrict__ biasAll,
                                                 u16* __restrict__ outb) {
  __shared__ __align__(16) u16 bs[400 * 32];
  int t = threadIdx.x;
  int l = t & 63, wv = t >> 6, ln = l & 15, q = l >> 4;
  int b = blockIdx.z;
  int h0 = blockIdx.y * 16, w0 = blockIdx.x * 16;

  // stage 20x20x32 bf16 tile (reflect), c-pair packed u32 writes, swizzled
  {
    int cp = t & 15;
    int px0 = t >> 4;
    int py = 0, pxx = px0;
    const float* xp0 = x + ((size_t)b * 32 + 2 * cp) * PLANE;
    const float* xp1 = xp0 + PLANE;
#pragma unroll
    for (int i = 0; i < 25; ++i) {
      int gh = reflect_idx(h0 - 2 + py, Hn);
      int gw = reflect_idx(w0 - 2 + pxx, Wn);
      float v0 = xp0[gh * Wn + gw];
      float v1 = xp1[gh * Wn + gw];
      int px = py * 20 + pxx;
      uint pk = (uint)f2b(v0) | ((uint)f2b(v1) << 16);
      *(uint*)((char*)bs + px * 64 + ((((cp >> 2) ^ (px & 3)) << 4)) + (cp & 3) * 4) = pk;
      pxx += 16;
      if (pxx >= 20) { pxx -= 20; py += 1; }
    }
  }
  __syncthreads();

  float4v acc[4][2];
#pragma unroll
  for (int i = 0; i < 4; ++i) {
    acc[i][0] = (float4v){0.f, 0.f, 0.f, 0.f};
    acc[i][1] = (float4v){0.f, 0.f, 0.f, 0.f};
  }

  const u16* Ab = A5c + (size_t)b * 25600;
#pragma unroll
  for (int ty = 0; ty < 5; ++ty) {
#pragma unroll
    for (int tx = 0; tx < 5; ++tx) {
      int tap = ty * 5 + tx;
      short8v af0 = *(const short8v*)&Ab[((size_t)tap * 32 + ln) * 32 + q * 8];
      short8v af1 = *(const short8v*)&Ab[((size_t)tap * 32 + 16 + ln) * 32 + q * 8];
#pragma unroll
      for (int r4 = 0; r4 < 4; ++r4) {
        int px = (wv * 4 + r4 + ty) * 20 + ln + tx;
        short8v bf = *(const short8v*)((const char*)bs + px * 64 + ((q ^ (px & 3)) << 4));
        acc[r4][0] = __builtin_amdgcn_mfma_f32_16x16x32_bf16(af0, bf, acc[r4][0], 0, 0, 0);
        acc[r4][1] = __builtin_amdgcn_mfma_f32_16x16x32_bf16(af1, bf, acc[r4][1], 0, 0, 0);
      }
    }
  }

  // fused maxpool 2x2 epilogue -> p1 (256x256 NHWC)
  const float* bias = biasAll + b * 32;
#pragma unroll
  for (int rp = 0; rp < 2; ++rp) {
#pragma unroll
    for (int g = 0; g < 2; ++g) {
      float m0 = fmaxf(acc[2 * rp][g][0], acc[2 * rp + 1][g][0]);
      float m1 = fmaxf(acc[2 * rp][g][1], acc[2 * rp + 1][g][1]);
      float m2 = fmaxf(acc[2 * rp][g][2], acc[2 * rp + 1][g][2]);
      float m3 = fmaxf(acc[2 * rp][g][3], acc[2 * rp + 1][g][3]);
      m0 = fmaxf(m0, __shfl_xor(m0, 1));
      m1 = fmaxf(m1, __shfl_xor(m1, 1));
      m2 = fmaxf(m2, __shfl_xor(m2, 1));
      m3 = fmaxf(m3, __shfl_xor(m3, 1));
      if (!(l & 1)) {
        int ph = (h0 >> 1) + wv * 2 + rp;
        int pw = (w0 >> 1) + (ln >> 1);
        uint2 pk;
        pk.x = (uint)f2b(m0 + bias[g * 16 + q * 4 + 0]) |
               ((uint)f2b(m1 + bias[g * 16 + q * 4 + 1]) << 16);
        pk.y = (uint)f2b(m2 + bias[g * 16 + q * 4 + 2]) |
               ((uint)f2b(m3 + bias[g * 16 + q * 4 + 3]) << 16);
        *(uint2*)&outb[(((size_t)b * 256 + ph) * 256 + pw) * 32 + g * 16 + q * 4] = pk;
      }
    }
  }
}

// ---------------------------------------------------------------------------
// Border fix: recompute the 1020 perimeter pooled cells per sample exactly
// (reference semantics: reflect-101 branch maps, conv1 zero-pad, pool).
// Grid (64, 4); block 256 = 64 px-lanes x 4 oc-quads (wave-uniform quad).
// ---------------------------------------------------------------------------
__global__ void __launch_bounds__(256) k_border(const float* __restrict__ x,
                                                const float* __restrict__ w1,
                                                const float* __restrict__ b1,
                                                const float* __restrict__ stats,
                                                u16* __restrict__ p1) {
  int t = threadIdx.x;
  int lane = t & 63, quad = t >> 6;
  int b = blockIdx.y;
  int p = blockIdx.x * 64 + lane;
  if (p >= 4080) return;
  int cell = p >> 2, k = p & 3;
  int ph, pw;
  if (cell < 256) { ph = 0; pw = cell; }
  else if (cell < 512) { ph = 255; pw = cell - 256; }
  else if (cell < 766) { ph = 1 + (cell - 512); pw = 0; }
  else { ph = 1 + (cell - 766); pw = 255; }
  int h = 2 * ph + (k >> 1), w = 2 * pw + (k & 1);

  float mean[5], istd[5];
#pragma unroll
  for (int br = 0; br < 5; ++br) {
    mean[br] = stats[(b * 5 + br) * 2];
    istd[br] = stats[(b * 5 + br) * 2 + 1];
  }

  float acc[8];
#pragma unroll
  for (int i = 0; i < 8; ++i) acc[i] = 0.f;

  for (int c = 0; c < 32; ++c) {
    const float* xp = x + (size_t)(b * 32 + c) * PLANE;
    float xw[5][5];
#pragma unroll
    for (int dy = 0; dy < 5; ++dy) {
      int gh = reflect_idx(h - 2 + dy, Hn);
#pragma unroll
      for (int dx = 0; dx < 5; ++dx) {
        int gw = reflect_idx(w - 2 + dx, Wn);
        xw[dy][dx] = xp[gh * Wn + gw];
      }
    }
    float Bnv[5][9];
#pragma unroll
    for (int ty = 0; ty < 3; ++ty) {
#pragma unroll
      for (int tx = 0; tx < 3; ++tx) {
        int hh = h + ty - 1, ww = w + tx - 1;
        bool valid = (hh >= 0 && hh < Hn && ww >= 0 && ww < Wn);
        float v1, v2, v3, v4, v5;
        BRANCH_VALS(xw[ty][tx], xw[ty][tx + 1], xw[ty][tx + 2],
                    xw[ty + 1][tx], xw[ty + 1][tx + 1], xw[ty + 1][tx + 2],
                    xw[ty + 2][tx], xw[ty + 2][tx + 1], xw[ty + 2][tx + 2],
                    v1, v2, v3, v4, v5);
        int tap = ty * 3 + tx;
        Bnv[0][tap] = valid ? (v1 - mean[0]) * istd[0] : 0.f;
        Bnv[1][tap] = valid ? (v2 - mean[1]) * istd[1] : 0.f;
        Bnv[2][tap] = valid ? (v3 - mean[2]) * istd[2] : 0.f;
        Bnv[3][tap] = valid ? (v4 - mean[3]) * istd[3] : 0.f;
        Bnv[4][tap] = valid ? (v5 - mean[4]) * istd[4] : 0.f;
      }
    }
#pragma unroll
    for (int br = 0; br < 5; ++br) {
#pragma unroll
      for (int oc8 = 0; oc8 < 8; ++oc8) {
        int oc = quad * 8 + oc8;
        const float* wp = w1 + ((size_t)oc * 160 + br * 32 + c) * 9;  // wave-uniform
        float a0 = acc[oc8];
#pragma unroll
        for (int tap = 0; tap < 9; ++tap) a0 = fmaf(wp[tap], Bnv[br][tap], a0);
        acc[oc8] = a0;
      }
    }
  }

  u16 r[8];
#pragma unroll
  for (int oc8 = 0; oc8 < 8; ++oc8) {
    float m = acc[oc8] + b1[quad * 8 + oc8];
    m = fmaxf(m, __shfl_xor(m, 1));
    m = fmaxf(m, __shfl_xor(m, 2));
    r[oc8] = f2b(m);
  }
  if (k == 0)
    *(uint4*)&p1[(((size_t)b * 256 + ph) * 256 + pw) * 32 + quad * 8] = *(uint4*)r;
}

// ---------------------------------------------------------------------------
// Generic 3x3 MFMA conv, NHWC bf16 in. MODE 0: bf16 NHWC out.
// MODE 1: fp32 NCHW out * xorig (two-pass 16-oc LDS transpose epilogue).
// MODE 2: fused maxpool2x2 -> bf16 NHWC out at (H/2, W/2).
// ---------------------------------------------------------------------------
template <int CIN, int MODE>
__global__ void __launch_bounds__(256) k_conv_mfma(const u16* __restrict__ in,
                                                   const u16* __restrict__ Aw,
                                                   const float* __restrict__ bias,
                                                   u16* __restrict__ outb,
                                                   float* __restrict__ outf,
                                                   const float* __restrict__ xorig,
                                                   int H, int W) {
  constexpr int ICC = CIN / 32;
  __shared__ __align__(16) char smem[20736];
  u16* bs = (u16*)smem;
  int t = threadIdx.x;
  int l = t & 63, wv = t >> 6;
  int ln = l & 15, q = l >> 4;
  int bz = blockIdx.z;
  int h0 = blockIdx.y * 16, w0 = blockIdx.x * 16;

  float4v acc[4][2];
#pragma unroll
  for (int i = 0; i < 4; ++i) {
    acc[i][0] = (float4v){0.f, 0.f, 0.f, 0.f};
    acc[i][1] = (float4v){0.f, 0.f, 0.f, 0.f};
  }

  for (int icc = 0; icc < ICC; ++icc) {
    for (int u = t; u < 1296; u += 256) {
      int px = u >> 2, sq = u & 3;
      int ry = px / 18, rx = px - ry * 18;
      int gh = h0 - 1 + ry, gw = w0 - 1 + rx;
      uint4 v = {0, 0, 0, 0};
      if (gh >= 0 && gh < H && gw >= 0 && gw < W)
        v = *(const uint4*)&in[(((size_t)bz * H + gh) * W + gw) * CIN + icc * 32 + sq * 8];
      *(uint4*)((char*)bs + px * 64 + ((sq ^ (px & 3)) << 4)) = v;
    }
    short8v af[9][2];
#pragma unroll
    for (int tp = 0; tp < 9; ++tp) {
      af[tp][0] = *(const short8v*)&Aw[((size_t)(icc * 9 + tp) * 32 + ln) * 32 + q * 8];
      af[tp][1] = *(const short8v*)&Aw[((size_t)(icc * 9 + tp) * 32 + 16 + ln) * 32 + q * 8];
    }
    __syncthreads();
#pragma unroll
    for (int r4 = 0; r4 < 4; ++r4) {
      int r = wv * 4 + r4;
#pragma unroll
      for (int dy = 0; dy < 3; ++dy) {
#pragma unroll
        for (int dx = 0; dx < 3; ++dx) {
          int px = (r + dy) * 18 + ln + dx;
          short8v bf = *(const short8v*)((const char*)bs + px * 64 + ((q ^ (px & 3)) << 4));
          acc[r4][0] = __builtin_amdgcn_mfma_f32_16x16x32_bf16(af[dy * 3 + dx][0], bf, acc[r4][0], 0, 0, 0);
          acc[r4][1] = __builtin_amdgcn_mfma_f32_16x16x32_bf16(af[dy * 3 + dx][1], bf, acc[r4][1], 0, 0, 0);
        }
      }
    }
    if (ICC > 1) __syncthreads();
  }

  if (MODE == 0) {
#pragma unroll
    for (int r4 = 0; r4 < 4; ++r4) {
      int h = h0 + wv * 4 + r4;
      int wpix = w0 + ln;
#pragma unroll
      for (int g = 0; g < 2; ++g) {
        float v0 = acc[r4][g][0] + bias[g * 16 + q * 4 + 0];
        float v1 = acc[r4][g][1] + bias[g * 16 + q * 4 + 1];
        float v2 = acc[r4][g][2] + bias[g * 16 + q * 4 + 2];
        float v3 = acc[r4][g][3] + bias[g * 16 + q * 4 + 3];
        uint2 pk;
        pk.x = (uint)f2b(v0) | ((uint)f2b(v1) << 16);
        pk.y = (uint)f2b(v2) | ((uint)f2b(v3) << 16);
        *(uint2*)&outb[(((size_t)bz * H + h) * W + wpix) * 32 + g * 16 + q * 4] = pk;
      }
    }
  } else if (MODE == 2) {
    int Hp = H >> 1, Wp = W >> 1;
#pragma unroll
    for (int rp = 0; rp < 2; ++rp) {
#pragma unroll
      for (int g = 0; g < 2; ++g) {
        float m0 = fmaxf(acc[2 * rp][g][0], acc[2 * rp + 1][g][0]);
        float m1 = fmaxf(acc[2 * rp][g][1], acc[2 * rp + 1][g][1]);
        float m2 = fmaxf(acc[2 * rp][g][2], acc[2 * rp + 1][g][2]);
        float m3 = fmaxf(acc[2 * rp][g][3], acc[2 * rp + 1][g][3]);
        m0 = fmaxf(m0, __shfl_xor(m0, 1));
        m1 = fmaxf(m1, __shfl_xor(m1, 1));
        m2 = fmaxf(m2, __shfl_xor(m2, 1));
        m3 = fmaxf(m3, __shfl_xor(m3, 1));
        if (!(l & 1)) {
          int ph = (h0 >> 1) + wv * 2 + rp;
          int pw = (w0 >> 1) + (ln >> 1);
          uint2 pk;
          pk.x = (uint)f2b(m0 + bias[g * 16 + q * 4 + 0]) |
                 ((uint)f2b(m1 + bias[g * 16 + q * 4 + 1]) << 16);
          pk.y = (uint)f2b(m2 + bias[g * 16 + q * 4 + 2]) |
                 ((uint)f2b(m3 + bias[g * 16 + q * 4 + 3]) << 16);
          *(uint2*)&outb[(((size_t)bz * Hp + ph) * Wp + pw) * 32 + g * 16 + q * 4] = pk;
        }
      }
    }
  } else {
    // MODE 1: two-pass (16 oc each) LDS transpose, fused *xorig, fp32 NCHW
    float* os = (float*)smem;  // [ocl16][h16][w 20-stride] = 20480 B
#pragma unroll
    for (int g = 0; g < 2; ++g) {
      __syncthreads();
#pragma unroll
      for (int r4 = 0; r4 < 4; ++r4) {
        int hl = wv * 4 + r4;
#pragma unroll
        for (int i = 0; i < 4; ++i) {
          int ocl = q * 4 + i;
          os[(ocl * 16 + hl) * 20 + ln] = acc[r4][g][i] + bias[g * 16 + ocl];
        }
      }
      __syncthreads();
#pragma unroll
      for (int j = 0; j < 4; ++j) {
        int u = t + j * 256;  // 1024 float4 units
        int wq = u & 3, hh = (u >> 2) & 15, ocl = u >> 6;
        float4v v = *(const float4v*)&os[(ocl * 16 + hh) * 20 + wq * 4];
        size_t gidx = (((size_t)bz * 32 + g * 16 + ocl) * H + h0 + hh) * W + w0 + wq * 4;
        float4v xo = *(const float4v*)&xorig[gidx];
        v[0] *= xo[0]; v[1] *= xo[1]; v[2] *= xo[2]; v[3] *= xo[3];
        *(float4v*)&outf[gidx] = v;
      }
    }
  }
}

// ---------------------------------------------------------------------------
// deconv 2x2 s2 as 4 parity 1x1 GEMMs via MFMA.
// ---------------------------------------------------------------------------
__global__ void __launch_bounds__(256) k_deconv_mfma(const u16* __restrict__ in,
                                                     const u16* __restrict__ Aw,
                                                     const float* __restrict__ bias,
                                                     u16* __restrict__ out,
                                                     int Hi, int Wi) {
  int t = threadIdx.x;
  int l = t & 63, wv = t >> 6, ln = l & 15, q = l >> 4;
  int z = blockIdx.z, b = z >> 2, par = z & 3, p = par >> 1, qpar = par & 1;
  int h0 = blockIdx.y * 16, w0 = blockIdx.x * 16;
  int Ho = Hi * 2, Wo = Wi * 2;
  short8v af0 = *(const short8v*)&Aw[((size_t)par * 32 + ln) * 32 + q * 8];
  short8v af1 = *(const short8v*)&Aw[((size_t)par * 32 + 16 + ln) * 32 + q * 8];
#pragma unroll
  for (int r4 = 0; r4 < 4; ++r4) {
    int h = h0 + wv * 4 + r4;
    short8v bf = *(const short8v*)&in[(((size_t)b * Hi + h) * Wi + w0 + ln) * 32 + q * 8];
    float4v a0 = (float4v){0.f, 0.f, 0.f, 0.f};
    float4v a1 = (float4v){0.f, 0.f, 0.f, 0.f};
    a0 = __builtin_amdgcn_mfma_f32_16x16x32_bf16(af0, bf, a0, 0, 0, 0);
    a1 = __builtin_amdgcn_mfma_f32_16x16x32_bf16(af1, bf, a1, 0, 0, 0);
    int oh = 2 * h + p, ow = 2 * (w0 + ln) + qpar;
    size_t ob = (((size_t)b * Ho + oh) * Wo + ow) * 32;
    uint2 pk;
    pk.x = (uint)f2b(a0[0] + bias[q * 4 + 0]) | ((uint)f2b(a0[1] + bias[q * 4 + 1]) << 16);
    pk.y = (uint)f2b(a0[2] + bias[q * 4 + 2]) | ((uint)f2b(a0[3] + bias[q * 4 + 3]) << 16);
    *(uint2*)&out[ob + q * 4] = pk;
    pk.x = (uint)f2b(a1[0] + bias[16 + q * 4 + 0]) | ((uint)f2b(a1[1] + bias[16 + q * 4 + 1]) << 16);
    pk.y = (uint)f2b(a1[2] + bias[16 + q * 4 + 2]) | ((uint)f2b(a1[3] + bias[16 + q * 4 + 3]) << 16);
    *(uint2*)&out[ob + 16 + q * 4] = pk;
  }
}

// ---------------------------------------------------------------------------
extern "C" void kernel_launch(void* const* d_in, const int* in_sizes, int n_in,
                              void* d_out, int out_size, void* d_ws, size_t ws_size,
                              hipStream_t stream) {
  const float* x   = (const float*)d_in[0];
  const float* w1  = (const float*)d_in[1];
  const float* b1  = (const float*)d_in[2];
  const float* w2  = (const float*)d_in[3];
  const float* b2  = (const float*)d_in[4];
  const float* w3  = (const float*)d_in[5];
  const float* b3  = (const float*)d_in[6];
  const float* w4  = (const float*)d_in[7];
  const float* b4  = (const float*)d_in[8];
  const float* w5  = (const float*)d_in[9];
  const float* b5  = (const float*)d_in[10];
  const float* w6  = (const float*)d_in[11];
  const float* b6  = (const float*)d_in[12];
  const float* w7  = (const float*)d_in[13];
  const float* b7  = (const float*)d_in[14];
  const float* dw1 = (const float*)d_in[15];
  const float* db1 = (const float*)d_in[16];
  const float* dw2 = (const float*)d_in[17];
  const float* db2 = (const float*)d_in[18];
  const float* dw3 = (const float*)d_in[19];
  const float* db3 = (const float*)d_in[20];
  float* out = (float*)d_out;
  char* wsb = (char*)d_ws;

  u16* p1  = (u16*)(wsb + 0);               // 16,777,216
  u16* p2  = (u16*)(wsb + 16777216ull);     //  4,194,304
  u16* p3  = (u16*)(wsb + 20971520ull);     //  1,048,576
  u16* t4  = (u16*)(wsb + 22020096ull);     //  1,048,576
  u16* dc1 = (u16*)(wsb + 23068672ull);     //  4,194,304
  u16* t5  = (u16*)(wsb + 27262976ull);     //  4,194,304
  u16* dc2 = (u16*)(wsb + 31457280ull);     // 16,777,216
  u16* t6  = (u16*)(wsb + 48234496ull);     // 16,777,216
  u16* dc3 = (u16*)(wsb + 65011712ull);     // 67,108,864
  u16* A5c = (u16*)(wsb + 132120576ull);    //    204,800
  u16* A2  = (u16*)(wsb + 132325376ull);
  u16* A3  = (u16*)(wsb + 132343808ull);
  u16* A4  = (u16*)(wsb + 132362240ull);
  u16* A5  = (u16*)(wsb + 132380672ull);
  u16* A6  = (u16*)(wsb + 132399104ull);
  u16* A7  = (u16*)(wsb + 132417536ull);
  u16* Ad1 = (u16*)(wsb + 132435968ull);
  u16* Ad2 = (u16*)(wsb + 132444160ull);
  u16* Ad3 = (u16*)(wsb + 132452352ull);
  float* bias1all = (float*)(wsb + 132460544ull);
  float* partS    = (float*)(wsb + 132461056ull);
  float* partQ    = (float*)(wsb + 132788736ull);
  float* stats    = (float*)(wsb + 133116416ull);

  k_prep_shared<<<264, 256, 0, stream>>>(w2, w3, w4, w5, w6, w7, dw1, dw2, dw3,
                                         A2, A3, A4, A5, A6, A7, Ad1, Ad2, Ad3);
  k_opstats<<<8192, 128, 0, stream>>>(x, partS, partQ);
  k_stats<<<20, 256, 0, stream>>>(partS, partQ, stats);
  k_prep_conv1<<<401, 256, 0, stream>>>(w1, b1, stats, A5c, bias1all);

  // fused operator+conv1+pool (all samples), then exact border overwrite
  k_conv5x5<<<dim3(32, 32, 4), 256, 0, stream>>>(x, A5c, bias1all, p1);
  k_border<<<dim3(64, 4), 256, 0, stream>>>(x, w1, b1, stats, p1);

  k_conv_mfma<32, 2><<<dim3(16, 16, 4), 256, 0, stream>>>(p1, A2, b2, p2, nullptr, nullptr, 256, 256);
  k_conv_mfma<32, 2><<<dim3(8, 8, 4), 256, 0, stream>>>(p2, A3, b3, p3, nullptr, nullptr, 128, 128);
  k_conv_mfma<32, 0><<<dim3(4, 4, 4), 256, 0, stream>>>(p3, A4, b4, t4, nullptr, nullptr, 64, 64);
  k_deconv_mfma<<<dim3(4, 4, 16), 256, 0, stream>>>(t4, Ad1, db1, dc1, 64, 64);
  k_conv_mfma<32, 0><<<dim3(8, 8, 4), 256, 0, stream>>>(dc1, A5, b5, t5, nullptr, nullptr, 128, 128);
  k_deconv_mfma<<<dim3(8, 8, 16), 256, 0, stream>>>(t5, Ad2, db2, dc2, 128, 128);
  k_conv_mfma<32, 0><<<dim3(16, 16, 4), 256, 0, stream>>>(dc2, A6, b6, t6, nullptr, nullptr, 256, 256);
  k_deconv_mfma<<<dim3(16, 16, 16), 256, 0, stream>>>(t6, Ad3, db3, dc3, 256, 256);
  k_conv_mfma<32, 1><<<dim3(32, 32, 4), 256, 0, stream>>>(dc3, A7, b7, nullptr, out, x, 512, 512);
}

// Round 7
// 747.972 us; speedup vs baseline: 1.1329x; 1.1329x over previous
//
#include <hip/hip_runtime.h>
#include <hip/hip_bf16.h>
#include <cstddef>

// B=4, C=32, H=W=512. NHWC bf16 MFMA pipeline.
// conv1 o operator == 5x5 conv on x (composed weights) for interior tiles;
// perimeter 16x16 tiles are computed exactly by k_conv1_edge (branch maps
// built in LDS with conv1 zero-pad semantics, 3x3 MFMA with W1*istd).

typedef unsigned short u16;
typedef unsigned int uint;
typedef __attribute__((ext_vector_type(8))) short short8v;
typedef __attribute__((ext_vector_type(4))) float float4v;

constexpr int Bn = 4, Cn = 32, Hn = 512, Wn = 512;
constexpr int PLANE = Hn * Wn;

__device__ __forceinline__ float b2f(u16 u) {
  union { uint i; float f; } c; c.i = ((uint)u) << 16; return c.f;
}
__device__ __forceinline__ u16 f2b(float f) {
  union { float f; uint i; } c; c.f = f;
  uint r = c.i + 0x7FFFu + ((c.i >> 16) & 1u);
  return (u16)(r >> 16);
}

static __device__ __forceinline__ int reflect_idx(int i, int n) {
  return i < 0 ? -i : (i >= n ? 2 * n - 2 - i : i);
}

// Combined stencils (0.5*(Kx+Ky) folded); validated rounds 3-6.
#define BRANCH_VALS(n00, n01, n02, n10, n11, n12, n20, n21, n22, v1, v2, v3, v4, v5)        \
  do {                                                                                      \
    v1 = -(n00 + n01 + n10) + (n12 + n21 + n22);                                            \
    v2 = -3.f * n00 - 5.f * n01 - 5.f * n10 + 5.f * n12 + 5.f * n21 + 3.f * n22;            \
    v3 = 2.f * (n00 + n02 + n20 + n22) - 8.f * n11;                                         \
    v4 = 0.5f * (-n00 - n01 + n10 + n11);                                                   \
    v5 = 0.5f * n01 + n02 - 0.5f * n10 + 0.5f * n12 - n20 - 0.5f * n21;                     \
  } while (0)

// Stencil taps S_br[s*3+t]
__device__ const float Sdev[5][9] = {
    {-1.f, -1.f, 0.f, -1.f, 0.f, 1.f, 0.f, 1.f, 1.f},
    {-3.f, -5.f, 0.f, -5.f, 0.f, 5.f, 0.f, 5.f, 3.f},
    {2.f, 0.f, 2.f, 0.f, -8.f, 0.f, 2.f, 0.f, 2.f},
    {-0.5f, -0.5f, 0.f, 0.5f, 0.5f, 0.f, 0.f, 0.f, 0.f},
    {0.f, 0.5f, 1.f, -0.5f, 0.f, 0.5f, -1.f, -0.5f, 0.f}};

// ---------------------------------------------------------------------------
// Stats pass over x: per-(b,br) partial (sum, sumsq). Validated round 3.
// ---------------------------------------------------------------------------
__global__ void __launch_bounds__(128) k_opstats(const float* __restrict__ x,
                                                 float* __restrict__ partS,
                                                 float* __restrict__ partQ) {
  int bid = blockIdx.x;  // 8192
  int b = bid >> 11;
  int local = bid & 2047;
  int c = local >> 6;
  int chunk = local & 63;
  int t = threadIdx.x;
  int w0 = t * 4;
  const float* xp = x + (size_t)(b * Cn + c) * PLANE;
  int h0 = chunk * 8;

  int ci[6];
#pragma unroll
  for (int j = 0; j < 6; j++) ci[j] = reflect_idx(w0 - 1 + j, Wn);

  float ap[6], ac[6], an[6];
  {
    const float* rp = xp + reflect_idx(h0 - 1, Hn) * Wn;
#pragma unroll
    for (int j = 0; j < 6; j++) ap[j] = rp[ci[j]];
  }
  {
    const float* rp = xp + h0 * Wn;
#pragma unroll
    for (int j = 0; j < 6; j++) ac[j] = rp[ci[j]];
  }

  float s[5] = {0, 0, 0, 0, 0}, q[5] = {0, 0, 0, 0, 0};
#pragma unroll
  for (int r = 0; r < 8; ++r) {
    int h = h0 + r;
    const float* rp = xp + reflect_idx(h + 1, Hn) * Wn;
#pragma unroll
    for (int j = 0; j < 6; j++) an[j] = rp[ci[j]];
#pragma unroll
    for (int k = 0; k < 4; ++k) {
      float v1, v2, v3, v4, v5;
      BRANCH_VALS(ap[k], ap[k + 1], ap[k + 2], ac[k], ac[k + 1], ac[k + 2],
                  an[k], an[k + 1], an[k + 2], v1, v2, v3, v4, v5);
      s[0] += v1; q[0] += v1 * v1;
      s[1] += v2; q[1] += v2 * v2;
      s[2] += v3; q[2] += v3 * v3;
      s[3] += v4; q[3] += v4 * v4;
      s[4] += v5; q[4] += v5 * v5;
    }
#pragma unroll
    for (int j = 0; j < 6; j++) { ap[j] = ac[j]; ac[j] = an[j]; }
  }

#pragma unroll
  for (int i = 0; i < 5; i++) {
    float ss = s[i], qq = q[i];
#pragma unroll
    for (int off = 32; off > 0; off >>= 1) {
      ss += __shfl_down(ss, off);
      qq += __shfl_down(qq, off);
    }
    if ((t & 63) == 0) {
      int wv = t >> 6;
      int g = b * 5 + i;
      int idx = (c * 64 + chunk) * 2 + wv;
      partS[(size_t)g * 4096 + idx] = ss;
      partQ[(size_t)g * 4096 + idx] = qq;
    }
  }
}

__global__ void __launch_bounds__(256) k_stats(const float* __restrict__ partS,
                                               const float* __restrict__ partQ,
                                               float* __restrict__ stats) {
  __shared__ float red[256];
  int g = blockIdx.x;  // 20
  int t = threadIdx.x;
  float ss = 0.f, qq = 0.f;
  const float* ps = partS + (size_t)g * 4096;
  const float* pq = partQ + (size_t)g * 4096;
  for (int i = t; i < 4096; i += 256) {
    ss += ps[i];
    qq += pq[i];
  }
  red[t] = ss;
  __syncthreads();
  for (int o = 128; o > 0; o >>= 1) {
    if (t < o) red[t] += red[t + o];
    __syncthreads();
  }
  float S = red[0];
  __syncthreads();
  red[t] = qq;
  __syncthreads();
  for (int o = 128; o > 0; o >>= 1) {
    if (t < o) red[t] += red[t + o];
    __syncthreads();
  }
  if (t == 0) {
    const float N = 8388608.0f;
    float mean = S / N;
    float var = red[0] / N - mean * mean;
    stats[g * 2] = mean;
    stats[g * 2 + 1] = 1.0f / sqrtf(var);
  }
}

// ---------------------------------------------------------------------------
// Shared weight prep: conv2..7 -> A[tap][oc][ic]; deconv -> Adc[par][oc][ic].
// ---------------------------------------------------------------------------
__global__ void __launch_bounds__(256) k_prep_shared(
    const float* w2, const float* w3, const float* w4, const float* w5,
    const float* w6, const float* w7, const float* dw1, const float* dw2,
    const float* dw3, u16* A2, u16* A3, u16* A4, u16* A5, u16* A6, u16* A7,
    u16* Ad1, u16* Ad2, u16* Ad3) {
  int id = blockIdx.x * 256 + threadIdx.x;
  if (id < 55296) {
    int s = id / 9216, r = id % 9216;
    int tap = r / 1024, oc = (r >> 5) & 31, ic = r & 31;
    const float* w = s == 0 ? w2 : s == 1 ? w3 : s == 2 ? w4 : s == 3 ? w5 : s == 4 ? w6 : w7;
    u16* A = s == 0 ? A2 : s == 1 ? A3 : s == 2 ? A4 : s == 3 ? A5 : s == 4 ? A6 : A7;
    A[r] = f2b(w[(oc * 32 + ic) * 9 + tap]);
  } else if (id < 67584) {
    int r = id - 55296;
    int s = r / 4096, e = r % 4096;
    int par = e >> 10, oc = (e >> 5) & 31, ic = e & 31;
    const float* w = s == 0 ? dw1 : s == 1 ? dw2 : dw3;
    u16* A = s == 0 ? Ad1 : s == 1 ? Ad2 : Ad3;
    A[e] = f2b(w[(ic * 32 + oc) * 4 + par]);
  }
}

// ---------------------------------------------------------------------------
// conv1 prep: composed 5x5 weights A5c (interior), mean-folded bias1all,
// and normalized 3x3 weights A1n[b][br][tap][oc][ic] = W1*istd (edge tiles).
// ---------------------------------------------------------------------------
__global__ void __launch_bounds__(256) k_prep_conv1(const float* __restrict__ w1,
                                                    const float* __restrict__ b1,
                                                    const float* __restrict__ stats,
                                                    u16* __restrict__ A5c,
                                                    float* __restrict__ bias1all,
                                                    u16* __restrict__ A1n) {
  int e = blockIdx.x * 256 + threadIdx.x;
  if (e < 102400) {
    int b = e / 25600, r = e % 25600;
    int tap = r >> 10, oc = (r >> 5) & 31, ic = r & 31;
    int u = tap / 5, v = tap % 5;
    float acc = 0.f;
#pragma unroll
    for (int br = 0; br < 5; ++br) {
      float is = stats[(b * 5 + br) * 2 + 1];
      const float* wp = w1 + ((size_t)oc * 160 + br * 32 + ic) * 9;
      float sub = 0.f;
#pragma unroll
      for (int a = 0; a < 3; ++a) {
        int s = u - a;
        if (s < 0 || s > 2) continue;
#pragma unroll
        for (int bb = 0; bb < 3; ++bb) {
          int tt = v - bb;
          if (tt < 0 || tt > 2) continue;
          sub += wp[a * 3 + bb] * Sdev[br][s * 3 + tt];
        }
      }
      acc += is * sub;
    }
    A5c[e] = f2b(acc);
  } else if (e < 102528) {
    int t2 = e - 102400;
    int b = t2 >> 5, oc = t2 & 31;
    float s = 0.f;
    for (int ch = 0; ch < 160; ++ch) {
      int br = ch >> 5;
      float mi = stats[(b * 5 + br) * 2] * stats[(b * 5 + br) * 2 + 1];
      const float* wp = w1 + (size_t)(oc * 160 + ch) * 9;
      float ws = 0.f;
#pragma unroll
      for (int tap = 0; tap < 9; ++tap) ws += wp[tap];
      s += ws * mi;
    }
    bias1all[b * 32 + oc] = b1[oc] - s;
  } else if (e < 102528 + 184320) {
    int e2 = e - 102528;
    int b = e2 / 46080, r = e2 % 46080;
    int br = r / 9216, r2 = r % 9216;
    int tap = r2 / 1024, oc = (r2 >> 5) & 31, ic = r2 & 31;
    A1n[e2] = f2b(w1[((size_t)oc * 160 + br * 32 + ic) * 9 + tap] * stats[(b * 5 + br) * 2 + 1]);
  }
}

// ---------------------------------------------------------------------------
// Fused operator+conv1+pool (INTERIOR tiles): composed 5x5 MFMA conv on x,
// fused 2x2 maxpool -> p1 NHWC bf16. Perimeter tiles handled by k_conv1_edge.
// ---------------------------------------------------------------------------
__global__ void __launch_bounds__(256) k_conv5x5(const float* __restrict__ x,
                                                 const u16* __restrict__ A5c,
                                                 const float* __restrict__ biasAll,
                                                 u16* __restrict__ outb) {
  if (blockIdx.x == 0 || blockIdx.x == 31 || blockIdx.y == 0 || blockIdx.y == 31) return;
  __shared__ __align__(16) u16 bs[400 * 32];
  int t = threadIdx.x;
  int l = t & 63, wv = t >> 6, ln = l & 15, q = l >> 4;
  int b = blockIdx.z;
  int h0 = blockIdx.y * 16, w0 = blockIdx.x * 16;

  // stage 20x20x32 bf16 tile (reflect), c-pair packed u32 writes, swizzled
  {
    int cp = t & 15;
    int px0 = t >> 4;
    int py = 0, pxx = px0;
    const float* xp0 = x + ((size_t)b * 32 + 2 * cp) * PLANE;
    const float* xp1 = xp0 + PLANE;
#pragma unroll
    for (int i = 0; i < 25; ++i) {
      int gh = reflect_idx(h0 - 2 + py, Hn);
      int gw = reflect_idx(w0 - 2 + pxx, Wn);
      float v0 = xp0[gh * Wn + gw];
      float v1 = xp1[gh * Wn + gw];
      int px = py * 20 + pxx;
      uint pk = (uint)f2b(v0) | ((uint)f2b(v1) << 16);
      *(uint*)((char*)bs + px * 64 + ((((cp >> 2) ^ (px & 3)) << 4)) + (cp & 3) * 4) = pk;
      pxx += 16;
      if (pxx >= 20) { pxx -= 20; py += 1; }
    }
  }
  __syncthreads();

  float4v acc[4][2];
#pragma unroll
  for (int i = 0; i < 4; ++i) {
    acc[i][0] = (float4v){0.f, 0.f, 0.f, 0.f};
    acc[i][1] = (float4v){0.f, 0.f, 0.f, 0.f};
  }

  const u16* Ab = A5c + (size_t)b * 25600;
#pragma unroll
  for (int ty = 0; ty < 5; ++ty) {
#pragma unroll
    for (int tx = 0; tx < 5; ++tx) {
      int tap = ty * 5 + tx;
      short8v af0 = *(const short8v*)&Ab[((size_t)tap * 32 + ln) * 32 + q * 8];
      short8v af1 = *(const short8v*)&Ab[((size_t)tap * 32 + 16 + ln) * 32 + q * 8];
#pragma unroll
      for (int r4 = 0; r4 < 4; ++r4) {
        int px = (wv * 4 + r4 + ty) * 20 + ln + tx;
        short8v bf = *(const short8v*)((const char*)bs + px * 64 + ((q ^ (px & 3)) << 4));
        acc[r4][0] = __builtin_amdgcn_mfma_f32_16x16x32_bf16(af0, bf, acc[r4][0], 0, 0, 0);
        acc[r4][1] = __builtin_amdgcn_mfma_f32_16x16x32_bf16(af1, bf, acc[r4][1], 0, 0, 0);
      }
    }
  }

  const float* bias = biasAll + b * 32;
#pragma unroll
  for (int rp = 0; rp < 2; ++rp) {
#pragma unroll
    for (int g = 0; g < 2; ++g) {
      float m0 = fmaxf(acc[2 * rp][g][0], acc[2 * rp + 1][g][0]);
      float m1 = fmaxf(acc[2 * rp][g][1], acc[2 * rp + 1][g][1]);
      float m2 = fmaxf(acc[2 * rp][g][2], acc[2 * rp + 1][g][2]);
      float m3 = fmaxf(acc[2 * rp][g][3], acc[2 * rp + 1][g][3]);
      m0 = fmaxf(m0, __shfl_xor(m0, 1));
      m1 = fmaxf(m1, __shfl_xor(m1, 1));
      m2 = fmaxf(m2, __shfl_xor(m2, 1));
      m3 = fmaxf(m3, __shfl_xor(m3, 1));
      if (!(l & 1)) {
        int ph = (h0 >> 1) + wv * 2 + rp;
        int pw = (w0 >> 1) + (ln >> 1);
        uint2 pk;
        pk.x = (uint)f2b(m0 + bias[g * 16 + q * 4 + 0]) |
               ((uint)f2b(m1 + bias[g * 16 + q * 4 + 1]) << 16);
        pk.y = (uint)f2b(m2 + bias[g * 16 + q * 4 + 2]) |
               ((uint)f2b(m3 + bias[g * 16 + q * 4 + 3]) << 16);
        *(uint2*)&outb[(((size_t)b * 256 + ph) * 256 + pw) * 32 + g * 16 + q * 4] = pk;
      }
    }
  }
}

// ---------------------------------------------------------------------------
// EXACT edge-tile kernel: for the 124 perimeter 16x16 tiles per sample,
// build per-branch normalized branch tiles (B - mean, zeroed where conv1's
// zero-pad applies) in LDS and 3x3-MFMA with A1n = W1*istd. Fused pool.
// Grid (124, 4).
// ---------------------------------------------------------------------------
__global__ void __launch_bounds__(256) k_conv1_edge(const float* __restrict__ x,
                                                    const u16* __restrict__ A1n,
                                                    const float* __restrict__ b1,
                                                    const float* __restrict__ stats,
                                                    u16* __restrict__ outb) {
  __shared__ __align__(16) u16 xs[400 * 32];  // 25600 B
  __shared__ __align__(16) u16 bn[324 * 32];  // 20736 B
  int t = threadIdx.x;
  int l = t & 63, wv = t >> 6, ln = l & 15, q = l >> 4;
  int b = blockIdx.y;
  int bid = blockIdx.x;
  int th, tw;
  if (bid < 32) { th = 0; tw = bid; }
  else if (bid < 64) { th = 31; tw = bid - 32; }
  else if (bid < 94) { th = 1 + (bid - 64); tw = 0; }
  else { th = 1 + (bid - 94); tw = 31; }
  int h0 = th * 16, w0 = tw * 16;

  // stage x 20x20x32 bf16 (reflect), same packing as conv5x5
  {
    int cp = t & 15;
    int px0 = t >> 4;
    int py = 0, pxx = px0;
    const float* xp0 = x + ((size_t)b * 32 + 2 * cp) * PLANE;
    const float* xp1 = xp0 + PLANE;
#pragma unroll
    for (int i = 0; i < 25; ++i) {
      int gh = reflect_idx(h0 - 2 + py, Hn);
      int gw = reflect_idx(w0 - 2 + pxx, Wn);
      float v0 = xp0[gh * Wn + gw];
      float v1 = xp1[gh * Wn + gw];
      int px = py * 20 + pxx;
      uint pk = (uint)f2b(v0) | ((uint)f2b(v1) << 16);
      *(uint*)((char*)xs + px * 64 + ((((cp >> 2) ^ (px & 3)) << 4)) + (cp & 3) * 4) = pk;
      pxx += 16;
      if (pxx >= 20) { pxx -= 20; py += 1; }
    }
  }
  __syncthreads();

  float4v acc[4][2];
#pragma unroll
  for (int i = 0; i < 4; ++i) {
    acc[i][0] = (float4v){0.f, 0.f, 0.f, 0.f};
    acc[i][1] = (float4v){0.f, 0.f, 0.f, 0.f};
  }

  for (int br = 0; br < 5; ++br) {
    float mean = stats[(b * 5 + br) * 2];
    for (int u = t; u < 10368; u += 256) {
      int ic = u & 31, px = u >> 5;
      int r = px / 18, c = px - r * 18;
      float n00, n01, n02, n10, n11, n12, n20, n21, n22;
      {
        int p0 = r * 20 + c, p1 = p0 + 1, p2 = p0 + 2;
        int p3 = p0 + 20, p4 = p3 + 1, p5 = p3 + 2;
        int p6 = p3 + 20, p7 = p6 + 1, p8 = p6 + 2;
        int hi = (ic >> 3), lo = (ic & 7) * 2;
        n00 = b2f(*(const u16*)((const char*)xs + p0 * 64 + ((hi ^ (p0 & 3)) << 4) + lo));
        n01 = b2f(*(const u16*)((const char*)xs + p1 * 64 + ((hi ^ (p1 & 3)) << 4) + lo));
        n02 = b2f(*(const u16*)((const char*)xs + p2 * 64 + ((hi ^ (p2 & 3)) << 4) + lo));
        n10 = b2f(*(const u16*)((const char*)xs + p3 * 64 + ((hi ^ (p3 & 3)) << 4) + lo));
        n11 = b2f(*(const u16*)((const char*)xs + p4 * 64 + ((hi ^ (p4 & 3)) << 4) + lo));
        n12 = b2f(*(const u16*)((const char*)xs + p5 * 64 + ((hi ^ (p5 & 3)) << 4) + lo));
        n20 = b2f(*(const u16*)((const char*)xs + p6 * 64 + ((hi ^ (p6 & 3)) << 4) + lo));
        n21 = b2f(*(const u16*)((const char*)xs + p7 * 64 + ((hi ^ (p7 & 3)) << 4) + lo));
        n22 = b2f(*(const u16*)((const char*)xs + p8 * 64 + ((hi ^ (p8 & 3)) << 4) + lo));
      }
      float v;
      if (br == 0) v = -(n00 + n01 + n10) + (n12 + n21 + n22);
      else if (br == 1) v = -3.f * n00 - 5.f * n01 - 5.f * n10 + 5.f * n12 + 5.f * n21 + 3.f * n22;
      else if (br == 2) v = 2.f * (n00 + n02 + n20 + n22) - 8.f * n11;
      else if (br == 3) v = 0.5f * (-n00 - n01 + n10 + n11);
      else v = 0.5f * n01 + n02 - 0.5f * n10 + 0.5f * n12 - n20 - 0.5f * n21;
      int gh = h0 - 1 + r, gw = w0 - 1 + c;
      bool valid = (gh >= 0 && gh < Hn && gw >= 0 && gw < Wn);
      float outv = valid ? (v - mean) : 0.f;
      *(u16*)((char*)bn + px * 64 + (((ic >> 3) ^ (px & 3)) << 4) + (ic & 7) * 2) = f2b(outv);
    }
    __syncthreads();

    const u16* Ab = A1n + ((size_t)b * 5 + br) * 9216;
    short8v af[9][2];
#pragma unroll
    for (int tp = 0; tp < 9; ++tp) {
      af[tp][0] = *(const short8v*)&Ab[((size_t)tp * 32 + ln) * 32 + q * 8];
      af[tp][1] = *(const short8v*)&Ab[((size_t)tp * 32 + 16 + ln) * 32 + q * 8];
    }
#pragma unroll
    for (int r4 = 0; r4 < 4; ++r4) {
      int rr = wv * 4 + r4;
#pragma unroll
      for (int dy = 0; dy < 3; ++dy) {
#pragma unroll
        for (int dx = 0; dx < 3; ++dx) {
          int px = (rr + dy) * 18 + ln + dx;
          short8v bf = *(const short8v*)((const char*)bn + px * 64 + ((q ^ (px & 3)) << 4));
          acc[r4][0] = __builtin_amdgcn_mfma_f32_16x16x32_bf16(af[dy * 3 + dx][0], bf, acc[r4][0], 0, 0, 0);
          acc[r4][1] = __builtin_amdgcn_mfma_f32_16x16x32_bf16(af[dy * 3 + dx][1], bf, acc[r4][1], 0, 0, 0);
        }
      }
    }
    __syncthreads();
  }

  // fused pool epilogue; bias = plain b1 (mean already subtracted in bn)
#pragma unroll
  for (int rp = 0; rp < 2; ++rp) {
#pragma unroll
    for (int g = 0; g < 2; ++g) {
      float m0 = fmaxf(acc[2 * rp][g][0], acc[2 * rp + 1][g][0]);
      float m1 = fmaxf(acc[2 * rp][g][1], acc[2 * rp + 1][g][1]);
      float m2 = fmaxf(acc[2 * rp][g][2], acc[2 * rp + 1][g][2]);
      float m3 = fmaxf(acc[2 * rp][g][3], acc[2 * rp + 1][g][3]);
      m0 = fmaxf(m0, __shfl_xor(m0, 1));
      m1 = fmaxf(m1, __shfl_xor(m1, 1));
      m2 = fmaxf(m2, __shfl_xor(m2, 1));
      m3 = fmaxf(m3, __shfl_xor(m3, 1));
      if (!(l & 1)) {
        int ph = (h0 >> 1) + wv * 2 + rp;
        int pw = (w0 >> 1) + (ln >> 1);
        uint2 pk;
        pk.x = (uint)f2b(m0 + b1[g * 16 + q * 4 + 0]) |
               ((uint)f2b(m1 + b1[g * 16 + q * 4 + 1]) << 16);
        pk.y = (uint)f2b(m2 + b1[g * 16 + q * 4 + 2]) |
               ((uint)f2b(m3 + b1[g * 16 + q * 4 + 3]) << 16);
        *(uint2*)&outb[(((size_t)b * 256 + ph) * 256 + pw) * 32 + g * 16 + q * 4] = pk;
      }
    }
  }
}

// ---------------------------------------------------------------------------
// Generic 3x3 MFMA conv, NHWC bf16 in. MODE 0: bf16 NHWC out.
// MODE 1: fp32 NCHW out * xorig (two-pass 16-oc LDS transpose epilogue).
// MODE 2: fused maxpool2x2 -> bf16 NHWC out at (H/2, W/2).
// ---------------------------------------------------------------------------
template <int CIN, int MODE>
__global__ void __launch_bounds__(256) k_conv_mfma(const u16* __restrict__ in,
                                                   const u16* __restrict__ Aw,
                                                   const float* __restrict__ bias,
                                                   u16* __restrict__ outb,
                                                   float* __restrict__ outf,
                                                   const float* __restrict__ xorig,
                                                   int H, int W) {
  constexpr int ICC = CIN / 32;
  __shared__ __align__(16) char smem[20736];
  u16* bs = (u16*)smem;
  int t = threadIdx.x;
  int l = t & 63, wv = t >> 6;
  int ln = l & 15, q = l >> 4;
  int bz = blockIdx.z;
  int h0 = blockIdx.y * 16, w0 = blockIdx.x * 16;

  float4v acc[4][2];
#pragma unroll
  for (int i = 0; i < 4; ++i) {
    acc[i][0] = (float4v){0.f, 0.f, 0.f, 0.f};
    acc[i][1] = (float4v){0.f, 0.f, 0.f, 0.f};
  }

  for (int icc = 0; icc < ICC; ++icc) {
    for (int u = t; u < 1296; u += 256) {
      int px = u >> 2, sq = u & 3;
      int ry = px / 18, rx = px - ry * 18;
      int gh = h0 - 1 + ry, gw = w0 - 1 + rx;
      uint4 v = {0, 0, 0, 0};
      if (gh >= 0 && gh < H && gw >= 0 && gw < W)
        v = *(const uint4*)&in[(((size_t)bz * H + gh) * W + gw) * CIN + icc * 32 + sq * 8];
      *(uint4*)((char*)bs + px * 64 + ((sq ^ (px & 3)) << 4)) = v;
    }
    short8v af[9][2];
#pragma unroll
    for (int tp = 0; tp < 9; ++tp) {
      af[tp][0] = *(const short8v*)&Aw[((size_t)(icc * 9 + tp) * 32 + ln) * 32 + q * 8];
      af[tp][1] = *(const short8v*)&Aw[((size_t)(icc * 9 + tp) * 32 + 16 + ln) * 32 + q * 8];
    }
    __syncthreads();
#pragma unroll
    for (int r4 = 0; r4 < 4; ++r4) {
      int r = wv * 4 + r4;
#pragma unroll
      for (int dy = 0; dy < 3; ++dy) {
#pragma unroll
        for (int dx = 0; dx < 3; ++dx) {
          int px = (r + dy) * 18 + ln + dx;
          short8v bf = *(const short8v*)((const char*)bs + px * 64 + ((q ^ (px & 3)) << 4));
          acc[r4][0] = __builtin_amdgcn_mfma_f32_16x16x32_bf16(af[dy * 3 + dx][0], bf, acc[r4][0], 0, 0, 0);
          acc[r4][1] = __builtin_amdgcn_mfma_f32_16x16x32_bf16(af[dy * 3 + dx][1], bf, acc[r4][1], 0, 0, 0);
        }
      }
    }
    if (ICC > 1) __syncthreads();
  }

  if (MODE == 0) {
#pragma unroll
    for (int r4 = 0; r4 < 4; ++r4) {
      int h = h0 + wv * 4 + r4;
      int wpix = w0 + ln;
#pragma unroll
      for (int g = 0; g < 2; ++g) {
        float v0 = acc[r4][g][0] + bias[g * 16 + q * 4 + 0];
        float v1 = acc[r4][g][1] + bias[g * 16 + q * 4 + 1];
        float v2 = acc[r4][g][2] + bias[g * 16 + q * 4 + 2];
        float v3 = acc[r4][g][3] + bias[g * 16 + q * 4 + 3];
        uint2 pk;
        pk.x = (uint)f2b(v0) | ((uint)f2b(v1) << 16);
        pk.y = (uint)f2b(v2) | ((uint)f2b(v3) << 16);
        *(uint2*)&outb[(((size_t)bz * H + h) * W + wpix) * 32 + g * 16 + q * 4] = pk;
      }
    }
  } else if (MODE == 2) {
    int Hp = H >> 1, Wp = W >> 1;
#pragma unroll
    for (int rp = 0; rp < 2; ++rp) {
#pragma unroll
      for (int g = 0; g < 2; ++g) {
        float m0 = fmaxf(acc[2 * rp][g][0], acc[2 * rp + 1][g][0]);
        float m1 = fmaxf(acc[2 * rp][g][1], acc[2 * rp + 1][g][1]);
        float m2 = fmaxf(acc[2 * rp][g][2], acc[2 * rp + 1][g][2]);
        float m3 = fmaxf(acc[2 * rp][g][3], acc[2 * rp + 1][g][3]);
        m0 = fmaxf(m0, __shfl_xor(m0, 1));
        m1 = fmaxf(m1, __shfl_xor(m1, 1));
        m2 = fmaxf(m2, __shfl_xor(m2, 1));
        m3 = fmaxf(m3, __shfl_xor(m3, 1));
        if (!(l & 1)) {
          int ph = (h0 >> 1) + wv * 2 + rp;
          int pw = (w0 >> 1) + (ln >> 1);
          uint2 pk;
          pk.x = (uint)f2b(m0 + bias[g * 16 + q * 4 + 0]) |
                 ((uint)f2b(m1 + bias[g * 16 + q * 4 + 1]) << 16);
          pk.y = (uint)f2b(m2 + bias[g * 16 + q * 4 + 2]) |
                 ((uint)f2b(m3 + bias[g * 16 + q * 4 + 3]) << 16);
          *(uint2*)&outb[(((size_t)bz * Hp + ph) * Wp + pw) * 32 + g * 16 + q * 4] = pk;
        }
      }
    }
  } else {
    // MODE 1: two-pass (16 oc each) LDS transpose, fused *xorig, fp32 NCHW
    float* os = (float*)smem;  // [ocl16][h16][w 20-stride] = 20480 B
#pragma unroll
    for (int g = 0; g < 2; ++g) {
      __syncthreads();
#pragma unroll
      for (int r4 = 0; r4 < 4; ++r4) {
        int hl = wv * 4 + r4;
#pragma unroll
        for (int i = 0; i < 4; ++i) {
          int ocl = q * 4 + i;
          os[(ocl * 16 + hl) * 20 + ln] = acc[r4][g][i] + bias[g * 16 + ocl];
        }
      }
      __syncthreads();
#pragma unroll
      for (int j = 0; j < 4; ++j) {
        int u = t + j * 256;  // 1024 float4 units
        int wq = u & 3, hh = (u >> 2) & 15, ocl = u >> 6;
        float4v v = *(const float4v*)&os[(ocl * 16 + hh) * 20 + wq * 4];
        size_t gidx = (((size_t)bz * 32 + g * 16 + ocl) * H + h0 + hh) * W + w0 + wq * 4;
        float4v xo = *(const float4v*)&xorig[gidx];
        v[0] *= xo[0]; v[1] *= xo[1]; v[2] *= xo[2]; v[3] *= xo[3];
        *(float4v*)&outf[gidx] = v;
      }
    }
  }
}

// ---------------------------------------------------------------------------
// deconv 2x2 s2 as 4 parity 1x1 GEMMs via MFMA.
// ---------------------------------------------------------------------------
__global__ void __launch_bounds__(256) k_deconv_mfma(const u16* __restrict__ in,
                                                     const u16* __restrict__ Aw,
                                                     const float* __restrict__ bias,
                                                     u16* __restrict__ out,
                                                     int Hi, int Wi) {
  int t = threadIdx.x;
  int l = t & 63, wv = t >> 6, ln = l & 15, q = l >> 4;
  int z = blockIdx.z, b = z >> 2, par = z & 3, p = par >> 1, qpar = par & 1;
  int h0 = blockIdx.y * 16, w0 = blockIdx.x * 16;
  int Ho = Hi * 2, Wo = Wi * 2;
  short8v af0 = *(const short8v*)&Aw[((size_t)par * 32 + ln) * 32 + q * 8];
  short8v af1 = *(const short8v*)&Aw[((size_t)par * 32 + 16 + ln) * 32 + q * 8];
#pragma unroll
  for (int r4 = 0; r4 < 4; ++r4) {
    int h = h0 + wv * 4 + r4;
    short8v bf = *(const short8v*)&in[(((size_t)b * Hi + h) * Wi + w0 + ln) * 32 + q * 8];
    float4v a0 = (float4v){0.f, 0.f, 0.f, 0.f};
    float4v a1 = (float4v){0.f, 0.f, 0.f, 0.f};
    a0 = __builtin_amdgcn_mfma_f32_16x16x32_bf16(af0, bf, a0, 0, 0, 0);
    a1 = __builtin_amdgcn_mfma_f32_16x16x32_bf16(af1, bf, a1, 0, 0, 0);
    int oh = 2 * h + p, ow = 2 * (w0 + ln) + qpar;
    size_t ob = (((size_t)b * Ho + oh) * Wo + ow) * 32;
    uint2 pk;
    pk.x = (uint)f2b(a0[0] + bias[q * 4 + 0]) | ((uint)f2b(a0[1] + bias[q * 4 + 1]) << 16);
    pk.y = (uint)f2b(a0[2] + bias[q * 4 + 2]) | ((uint)f2b(a0[3] + bias[q * 4 + 3]) << 16);
    *(uint2*)&out[ob + q * 4] = pk;
    pk.x = (uint)f2b(a1[0] + bias[16 + q * 4 + 0]) | ((uint)f2b(a1[1] + bias[16 + q * 4 + 1]) << 16);
    pk.y = (uint)f2b(a1[2] + bias[16 + q * 4 + 2]) | ((uint)f2b(a1[3] + bias[16 + q * 4 + 3]) << 16);
    *(uint2*)&out[ob + 16 + q * 4] = pk;
  }
}

// ---------------------------------------------------------------------------
extern "C" void kernel_launch(void* const* d_in, const int* in_sizes, int n_in,
                              void* d_out, int out_size, void* d_ws, size_t ws_size,
                              hipStream_t stream) {
  const float* x   = (const float*)d_in[0];
  const float* w1  = (const float*)d_in[1];
  const float* b1  = (const float*)d_in[2];
  const float* w2  = (const float*)d_in[3];
  const float* b2  = (const float*)d_in[4];
  const float* w3  = (const float*)d_in[5];
  const float* b3  = (const float*)d_in[6];
  const float* w4  = (const float*)d_in[7];
  const float* b4  = (const float*)d_in[8];
  const float* w5  = (const float*)d_in[9];
  const float* b5  = (const float*)d_in[10];
  const float* w6  = (const float*)d_in[11];
  const float* b6  = (const float*)d_in[12];
  const float* w7  = (const float*)d_in[13];
  const float* b7  = (const float*)d_in[14];
  const float* dw1 = (const float*)d_in[15];
  const float* db1 = (const float*)d_in[16];
  const float* dw2 = (const float*)d_in[17];
  const float* db2 = (const float*)d_in[18];
  const float* dw3 = (const float*)d_in[19];
  const float* db3 = (const float*)d_in[20];
  float* out = (float*)d_out;
  char* wsb = (char*)d_ws;

  u16* p1  = (u16*)(wsb + 0);               // 16,777,216
  u16* p2  = (u16*)(wsb + 16777216ull);     //  4,194,304
  u16* p3  = (u16*)(wsb + 20971520ull);     //  1,048,576
  u16* t4  = (u16*)(wsb + 22020096ull);     //  1,048,576
  u16* dc1 = (u16*)(wsb + 23068672ull);     //  4,194,304
  u16* t5  = (u16*)(wsb + 27262976ull);     //  4,194,304
  u16* dc2 = (u16*)(wsb + 31457280ull);     // 16,777,216
  u16* t6  = (u16*)(wsb + 48234496ull);     // 16,777,216
  u16* dc3 = (u16*)(wsb + 65011712ull);     // 67,108,864
  u16* A5c = (u16*)(wsb + 132120576ull);    //    204,800
  u16* A2  = (u16*)(wsb + 132325376ull);
  u16* A3  = (u16*)(wsb + 132343808ull);
  u16* A4  = (u16*)(wsb + 132362240ull);
  u16* A5  = (u16*)(wsb + 132380672ull);
  u16* A6  = (u16*)(wsb + 132399104ull);
  u16* A7  = (u16*)(wsb + 132417536ull);
  u16* Ad1 = (u16*)(wsb + 132435968ull);
  u16* Ad2 = (u16*)(wsb + 132444160ull);
  u16* Ad3 = (u16*)(wsb + 132452352ull);
  float* bias1all = (float*)(wsb + 132460544ull);
  float* partS    = (float*)(wsb + 132461056ull);
  float* partQ    = (float*)(wsb + 132788736ull);
  float* stats    = (float*)(wsb + 133116416ull);
  u16* A1n        = (u16*)(wsb + 133116576ull);  // 368,640

  k_prep_shared<<<264, 256, 0, stream>>>(w2, w3, w4, w5, w6, w7, dw1, dw2, dw3,
                                         A2, A3, A4, A5, A6, A7, Ad1, Ad2, Ad3);
  k_opstats<<<8192, 128, 0, stream>>>(x, partS, partQ);
  k_stats<<<20, 256, 0, stream>>>(partS, partQ, stats);
  k_prep_conv1<<<1121, 256, 0, stream>>>(w1, b1, stats, A5c, bias1all, A1n);

  // fused operator+conv1+pool: interior composed 5x5, perimeter exact
  k_conv5x5<<<dim3(32, 32, 4), 256, 0, stream>>>(x, A5c, bias1all, p1);
  k_conv1_edge<<<dim3(124, 4), 256, 0, stream>>>(x, A1n, b1, stats, p1);

  k_conv_mfma<32, 2><<<dim3(16, 16, 4), 256, 0, stream>>>(p1, A2, b2, p2, nullptr, nullptr, 256, 256);
  k_conv_mfma<32, 2><<<dim3(8, 8, 4), 256, 0, stream>>>(p2, A3, b3, p3, nullptr, nullptr, 128, 128);
  k_conv_mfma<32, 0><<<dim3(4, 4, 4), 256, 0, stream>>>(p3, A4, b4, t4, nullptr, nullptr, 64, 64);
  k_deconv_mfma<<<dim3(4, 4, 16), 256, 0, stream>>>(t4, Ad1, db1, dc1, 64, 64);
  k_conv_mfma<32, 0><<<dim3(8, 8, 4), 256, 0, stream>>>(dc1, A5, b5, t5, nullptr, nullptr, 128, 128);
  k_deconv_mfma<<<dim3(8, 8, 16), 256, 0, stream>>>(t5, Ad2, db2, dc2, 128, 128);
  k_conv_mfma<32, 0><<<dim3(16, 16, 4), 256, 0, stream>>>(dc2, A6, b6, t6, nullptr, nullptr, 256, 256);
  k_deconv_mfma<<<dim3(16, 16, 16), 256, 0, stream>>>(t6, Ad3, db3, dc3, 256, 256);
  k_conv_mfma<32, 1><<<dim3(32, 32, 4), 256, 0, stream>>>(dc3, A7, b7, nullptr, out, x, 512, 512);
}

// Round 8
// 688.747 us; speedup vs baseline: 1.2303x; 1.0860x over previous
//
#include <hip/hip_runtime.h>
#include <hip/hip_bf16.h>
#include <cstddef>

// B=4, C=32, H=W=512. NHWC bf16 MFMA pipeline.
// conv1 o operator == 5x5 conv on x (composed weights) for interior tiles;
// perimeter 16x16 tiles are computed exactly by k_conv1_edge (branch maps
// built in LDS with conv1 zero-pad semantics, 3x3 MFMA with W1*istd).

typedef unsigned short u16;
typedef unsigned int uint;
typedef __attribute__((ext_vector_type(8))) short short8v;
typedef __attribute__((ext_vector_type(4))) float float4v;

struct __attribute__((packed, aligned(4))) f4u { float x, y, z, w; };

constexpr int Bn = 4, Cn = 32, Hn = 512, Wn = 512;
constexpr int PLANE = Hn * Wn;

__device__ __forceinline__ float b2f(u16 u) {
  union { uint i; float f; } c; c.i = ((uint)u) << 16; return c.f;
}
__device__ __forceinline__ u16 f2b(float f) {
  union { float f; uint i; } c; c.f = f;
  uint r = c.i + 0x7FFFu + ((c.i >> 16) & 1u);
  return (u16)(r >> 16);
}

static __device__ __forceinline__ int reflect_idx(int i, int n) {
  return i < 0 ? -i : (i >= n ? 2 * n - 2 - i : i);
}

// Combined stencils (0.5*(Kx+Ky) folded); validated rounds 3-7.
#define BRANCH_VALS(n00, n01, n02, n10, n11, n12, n20, n21, n22, v1, v2, v3, v4, v5)        \
  do {                                                                                      \
    v1 = -(n00 + n01 + n10) + (n12 + n21 + n22);                                            \
    v2 = -3.f * n00 - 5.f * n01 - 5.f * n10 + 5.f * n12 + 5.f * n21 + 3.f * n22;            \
    v3 = 2.f * (n00 + n02 + n20 + n22) - 8.f * n11;                                         \
    v4 = 0.5f * (-n00 - n01 + n10 + n11);                                                   \
    v5 = 0.5f * n01 + n02 - 0.5f * n10 + 0.5f * n12 - n20 - 0.5f * n21;                     \
  } while (0)

// Stencil taps S_br[s*3+t]
__device__ const float Sdev[5][9] = {
    {-1.f, -1.f, 0.f, -1.f, 0.f, 1.f, 0.f, 1.f, 1.f},
    {-3.f, -5.f, 0.f, -5.f, 0.f, 5.f, 0.f, 5.f, 3.f},
    {2.f, 0.f, 2.f, 0.f, -8.f, 0.f, 2.f, 0.f, 2.f},
    {-0.5f, -0.5f, 0.f, 0.5f, 0.5f, 0.f, 0.f, 0.f, 0.f},
    {0.f, 0.5f, 1.f, -0.5f, 0.f, 0.5f, -1.f, -0.5f, 0.f}};

// ---------------------------------------------------------------------------
// Stats pass over x: per-(b,br) partial (sum, sumsq). Validated round 3.
// ---------------------------------------------------------------------------
__global__ void __launch_bounds__(128) k_opstats(const float* __restrict__ x,
                                                 float* __restrict__ partS,
                                                 float* __restrict__ partQ) {
  int bid = blockIdx.x;  // 8192
  int b = bid >> 11;
  int local = bid & 2047;
  int c = local >> 6;
  int chunk = local & 63;
  int t = threadIdx.x;
  int w0 = t * 4;
  const float* xp = x + (size_t)(b * Cn + c) * PLANE;
  int h0 = chunk * 8;

  int ci[6];
#pragma unroll
  for (int j = 0; j < 6; j++) ci[j] = reflect_idx(w0 - 1 + j, Wn);

  float ap[6], ac[6], an[6];
  {
    const float* rp = xp + reflect_idx(h0 - 1, Hn) * Wn;
#pragma unroll
    for (int j = 0; j < 6; j++) ap[j] = rp[ci[j]];
  }
  {
    const float* rp = xp + h0 * Wn;
#pragma unroll
    for (int j = 0; j < 6; j++) ac[j] = rp[ci[j]];
  }

  float s[5] = {0, 0, 0, 0, 0}, q[5] = {0, 0, 0, 0, 0};
#pragma unroll
  for (int r = 0; r < 8; ++r) {
    int h = h0 + r;
    const float* rp = xp + reflect_idx(h + 1, Hn) * Wn;
#pragma unroll
    for (int j = 0; j < 6; j++) an[j] = rp[ci[j]];
#pragma unroll
    for (int k = 0; k < 4; ++k) {
      float v1, v2, v3, v4, v5;
      BRANCH_VALS(ap[k], ap[k + 1], ap[k + 2], ac[k], ac[k + 1], ac[k + 2],
                  an[k], an[k + 1], an[k + 2], v1, v2, v3, v4, v5);
      s[0] += v1; q[0] += v1 * v1;
      s[1] += v2; q[1] += v2 * v2;
      s[2] += v3; q[2] += v3 * v3;
      s[3] += v4; q[3] += v4 * v4;
      s[4] += v5; q[4] += v5 * v5;
    }
#pragma unroll
    for (int j = 0; j < 6; j++) { ap[j] = ac[j]; ac[j] = an[j]; }
  }

#pragma unroll
  for (int i = 0; i < 5; i++) {
    float ss = s[i], qq = q[i];
#pragma unroll
    for (int off = 32; off > 0; off >>= 1) {
      ss += __shfl_down(ss, off);
      qq += __shfl_down(qq, off);
    }
    if ((t & 63) == 0) {
      int wv = t >> 6;
      int g = b * 5 + i;
      int idx = (c * 64 + chunk) * 2 + wv;
      partS[(size_t)g * 4096 + idx] = ss;
      partQ[(size_t)g * 4096 + idx] = qq;
    }
  }
}

__global__ void __launch_bounds__(256) k_stats(const float* __restrict__ partS,
                                               const float* __restrict__ partQ,
                                               float* __restrict__ stats) {
  __shared__ float red[256];
  int g = blockIdx.x;  // 20
  int t = threadIdx.x;
  float ss = 0.f, qq = 0.f;
  const float* ps = partS + (size_t)g * 4096;
  const float* pq = partQ + (size_t)g * 4096;
  for (int i = t; i < 4096; i += 256) {
    ss += ps[i];
    qq += pq[i];
  }
  red[t] = ss;
  __syncthreads();
  for (int o = 128; o > 0; o >>= 1) {
    if (t < o) red[t] += red[t + o];
    __syncthreads();
  }
  float S = red[0];
  __syncthreads();
  red[t] = qq;
  __syncthreads();
  for (int o = 128; o > 0; o >>= 1) {
    if (t < o) red[t] += red[t + o];
    __syncthreads();
  }
  if (t == 0) {
    const float N = 8388608.0f;
    float mean = S / N;
    float var = red[0] / N - mean * mean;
    stats[g * 2] = mean;
    stats[g * 2 + 1] = 1.0f / sqrtf(var);
  }
}

// ---------------------------------------------------------------------------
// Shared weight prep: conv2..7 -> A[tap][oc][ic]; deconv -> Adc[par][oc][ic].
// ---------------------------------------------------------------------------
__global__ void __launch_bounds__(256) k_prep_shared(
    const float* w2, const float* w3, const float* w4, const float* w5,
    const float* w6, const float* w7, const float* dw1, const float* dw2,
    const float* dw3, u16* A2, u16* A3, u16* A4, u16* A5, u16* A6, u16* A7,
    u16* Ad1, u16* Ad2, u16* Ad3) {
  int id = blockIdx.x * 256 + threadIdx.x;
  if (id < 55296) {
    int s = id / 9216, r = id % 9216;
    int tap = r / 1024, oc = (r >> 5) & 31, ic = r & 31;
    const float* w = s == 0 ? w2 : s == 1 ? w3 : s == 2 ? w4 : s == 3 ? w5 : s == 4 ? w6 : w7;
    u16* A = s == 0 ? A2 : s == 1 ? A3 : s == 2 ? A4 : s == 3 ? A5 : s == 4 ? A6 : A7;
    A[r] = f2b(w[(oc * 32 + ic) * 9 + tap]);
  } else if (id < 67584) {
    int r = id - 55296;
    int s = r / 4096, e = r % 4096;
    int par = e >> 10, oc = (e >> 5) & 31, ic = e & 31;
    const float* w = s == 0 ? dw1 : s == 1 ? dw2 : dw3;
    u16* A = s == 0 ? Ad1 : s == 1 ? Ad2 : Ad3;
    A[e] = f2b(w[(ic * 32 + oc) * 4 + par]);
  }
}

// ---------------------------------------------------------------------------
// conv1 prep: composed 5x5 weights A5c (interior), mean-folded bias1all,
// and normalized 3x3 weights A1n[b][br][tap][oc][ic] = W1*istd (edge tiles).
// ---------------------------------------------------------------------------
__global__ void __launch_bounds__(256) k_prep_conv1(const float* __restrict__ w1,
                                                    const float* __restrict__ b1,
                                                    const float* __restrict__ stats,
                                                    u16* __restrict__ A5c,
                                                    float* __restrict__ bias1all,
                                                    u16* __restrict__ A1n) {
  int e = blockIdx.x * 256 + threadIdx.x;
  if (e < 102400) {
    int b = e / 25600, r = e % 25600;
    int tap = r >> 10, oc = (r >> 5) & 31, ic = r & 31;
    int u = tap / 5, v = tap % 5;
    float acc = 0.f;
#pragma unroll
    for (int br = 0; br < 5; ++br) {
      float is = stats[(b * 5 + br) * 2 + 1];
      const float* wp = w1 + ((size_t)oc * 160 + br * 32 + ic) * 9;
      float sub = 0.f;
#pragma unroll
      for (int a = 0; a < 3; ++a) {
        int s = u - a;
        if (s < 0 || s > 2) continue;
#pragma unroll
        for (int bb = 0; bb < 3; ++bb) {
          int tt = v - bb;
          if (tt < 0 || tt > 2) continue;
          sub += wp[a * 3 + bb] * Sdev[br][s * 3 + tt];
        }
      }
      acc += is * sub;
    }
    A5c[e] = f2b(acc);
  } else if (e < 102528) {
    int t2 = e - 102400;
    int b = t2 >> 5, oc = t2 & 31;
    float s = 0.f;
    for (int ch = 0; ch < 160; ++ch) {
      int br = ch >> 5;
      float mi = stats[(b * 5 + br) * 2] * stats[(b * 5 + br) * 2 + 1];
      const float* wp = w1 + (size_t)(oc * 160 + ch) * 9;
      float ws = 0.f;
#pragma unroll
      for (int tap = 0; tap < 9; ++tap) ws += wp[tap];
      s += ws * mi;
    }
    bias1all[b * 32 + oc] = b1[oc] - s;
  } else if (e < 102528 + 184320) {
    int e2 = e - 102528;
    int b = e2 / 46080, r = e2 % 46080;
    int br = r / 9216, r2 = r % 9216;
    int tap = r2 / 1024, oc = (r2 >> 5) & 31, ic = r2 & 31;
    A1n[e2] = f2b(w1[((size_t)oc * 160 + br * 32 + ic) * 9 + tap] * stats[(b * 5 + br) * 2 + 1]);
  }
}

// ---------------------------------------------------------------------------
// Fused operator+conv1+pool (INTERIOR tiles): composed 5x5 MFMA conv on x,
// fused 2x2 maxpool -> p1 NHWC bf16. Perimeter tiles handled by k_conv1_edge.
// Staging: interior => no reflect; coalesced float4 row-segment loads
// (unit u = ch*100 + row*5 + seg; consecutive lanes read consecutive 16B).
// ---------------------------------------------------------------------------
__global__ void __launch_bounds__(256) k_conv5x5(const float* __restrict__ x,
                                                 const u16* __restrict__ A5c,
                                                 const float* __restrict__ biasAll,
                                                 u16* __restrict__ outb) {
  if (blockIdx.x == 0 || blockIdx.x == 31 || blockIdx.y == 0 || blockIdx.y == 31) return;
  __shared__ __align__(16) u16 bs[400 * 32];
  int t = threadIdx.x;
  int l = t & 63, wv = t >> 6, ln = l & 15, q = l >> 4;
  int b = blockIdx.z;
  int h0 = blockIdx.y * 16, w0 = blockIdx.x * 16;

  {
    const float* xb = x + (size_t)b * 32 * PLANE + (size_t)(h0 - 2) * Wn + (w0 - 2);
    for (int u = t; u < 3200; u += 256) {
      int seg = u % 5;
      int row = (u / 5) % 20;
      int ch = u / 100;
      f4u v = *(const f4u*)(xb + (size_t)ch * PLANE + row * Wn + seg * 4);
      int hi = ch >> 3, lo = (ch & 7) * 2;
      float vv[4] = {v.x, v.y, v.z, v.w};
#pragma unroll
      for (int j = 0; j < 4; ++j) {
        int px = row * 20 + seg * 4 + j;
        *(u16*)((char*)bs + px * 64 + ((hi ^ (px & 3)) << 4) + lo) = f2b(vv[j]);
      }
    }
  }
  __syncthreads();

  float4v acc[4][2];
#pragma unroll
  for (int i = 0; i < 4; ++i) {
    acc[i][0] = (float4v){0.f, 0.f, 0.f, 0.f};
    acc[i][1] = (float4v){0.f, 0.f, 0.f, 0.f};
  }

  const u16* Ab = A5c + (size_t)b * 25600;
#pragma unroll
  for (int ty = 0; ty < 5; ++ty) {
#pragma unroll
    for (int tx = 0; tx < 5; ++tx) {
      int tap = ty * 5 + tx;
      short8v af0 = *(const short8v*)&Ab[((size_t)tap * 32 + ln) * 32 + q * 8];
      short8v af1 = *(const short8v*)&Ab[((size_t)tap * 32 + 16 + ln) * 32 + q * 8];
#pragma unroll
      for (int r4 = 0; r4 < 4; ++r4) {
        int px = (wv * 4 + r4 + ty) * 20 + ln + tx;
        short8v bf = *(const short8v*)((const char*)bs + px * 64 + ((q ^ (px & 3)) << 4));
        acc[r4][0] = __builtin_amdgcn_mfma_f32_16x16x32_bf16(af0, bf, acc[r4][0], 0, 0, 0);
        acc[r4][1] = __builtin_amdgcn_mfma_f32_16x16x32_bf16(af1, bf, acc[r4][1], 0, 0, 0);
      }
    }
  }

  const float* bias = biasAll + b * 32;
#pragma unroll
  for (int rp = 0; rp < 2; ++rp) {
#pragma unroll
    for (int g = 0; g < 2; ++g) {
      float m0 = fmaxf(acc[2 * rp][g][0], acc[2 * rp + 1][g][0]);
      float m1 = fmaxf(acc[2 * rp][g][1], acc[2 * rp + 1][g][1]);
      float m2 = fmaxf(acc[2 * rp][g][2], acc[2 * rp + 1][g][2]);
      float m3 = fmaxf(acc[2 * rp][g][3], acc[2 * rp + 1][g][3]);
      m0 = fmaxf(m0, __shfl_xor(m0, 1));
      m1 = fmaxf(m1, __shfl_xor(m1, 1));
      m2 = fmaxf(m2, __shfl_xor(m2, 1));
      m3 = fmaxf(m3, __shfl_xor(m3, 1));
      if (!(l & 1)) {
        int ph = (h0 >> 1) + wv * 2 + rp;
        int pw = (w0 >> 1) + (ln >> 1);
        uint2 pk;
        pk.x = (uint)f2b(m0 + bias[g * 16 + q * 4 + 0]) |
               ((uint)f2b(m1 + bias[g * 16 + q * 4 + 1]) << 16);
        pk.y = (uint)f2b(m2 + bias[g * 16 + q * 4 + 2]) |
               ((uint)f2b(m3 + bias[g * 16 + q * 4 + 3]) << 16);
        *(uint2*)&outb[(((size_t)b * 256 + ph) * 256 + pw) * 32 + g * 16 + q * 4] = pk;
      }
    }
  }
}

// ---------------------------------------------------------------------------
// EXACT edge-tile kernel: perimeter 16x16 tiles; branch maps in LDS with
// conv1 zero-pad semantics; 3x3 MFMA with A1n = W1*istd. Fused pool.
// ---------------------------------------------------------------------------
__global__ void __launch_bounds__(256) k_conv1_edge(const float* __restrict__ x,
                                                    const u16* __restrict__ A1n,
                                                    const float* __restrict__ b1,
                                                    const float* __restrict__ stats,
                                                    u16* __restrict__ outb) {
  __shared__ __align__(16) u16 xs[400 * 32];  // 25600 B
  __shared__ __align__(16) u16 bn[324 * 32];  // 20736 B
  int t = threadIdx.x;
  int l = t & 63, wv = t >> 6, ln = l & 15, q = l >> 4;
  int b = blockIdx.y;
  int bid = blockIdx.x;
  int th, tw;
  if (bid < 32) { th = 0; tw = bid; }
  else if (bid < 64) { th = 31; tw = bid - 32; }
  else if (bid < 94) { th = 1 + (bid - 64); tw = 0; }
  else { th = 1 + (bid - 94); tw = 31; }
  int h0 = th * 16, w0 = tw * 16;

  {
    int cp = t & 15;
    int px0 = t >> 4;
    int py = 0, pxx = px0;
    const float* xp0 = x + ((size_t)b * 32 + 2 * cp) * PLANE;
    const float* xp1 = xp0 + PLANE;
#pragma unroll
    for (int i = 0; i < 25; ++i) {
      int gh = reflect_idx(h0 - 2 + py, Hn);
      int gw = reflect_idx(w0 - 2 + pxx, Wn);
      float v0 = xp0[gh * Wn + gw];
      float v1 = xp1[gh * Wn + gw];
      int px = py * 20 + pxx;
      uint pk = (uint)f2b(v0) | ((uint)f2b(v1) << 16);
      *(uint*)((char*)xs + px * 64 + ((((cp >> 2) ^ (px & 3)) << 4)) + (cp & 3) * 4) = pk;
      pxx += 16;
      if (pxx >= 20) { pxx -= 20; py += 1; }
    }
  }
  __syncthreads();

  float4v acc[4][2];
#pragma unroll
  for (int i = 0; i < 4; ++i) {
    acc[i][0] = (float4v){0.f, 0.f, 0.f, 0.f};
    acc[i][1] = (float4v){0.f, 0.f, 0.f, 0.f};
  }

  for (int br = 0; br < 5; ++br) {
    float mean = stats[(b * 5 + br) * 2];
    for (int u = t; u < 10368; u += 256) {
      int ic = u & 31, px = u >> 5;
      int r = px / 18, c = px - r * 18;
      float n00, n01, n02, n10, n11, n12, n20, n21, n22;
      {
        int p0 = r * 20 + c, p1 = p0 + 1, p2 = p0 + 2;
        int p3 = p0 + 20, p4 = p3 + 1, p5 = p3 + 2;
        int p6 = p3 + 20, p7 = p6 + 1, p8 = p6 + 2;
        int hi = (ic >> 3), lo = (ic & 7) * 2;
        n00 = b2f(*(const u16*)((const char*)xs + p0 * 64 + ((hi ^ (p0 & 3)) << 4) + lo));
        n01 = b2f(*(const u16*)((const char*)xs + p1 * 64 + ((hi ^ (p1 & 3)) << 4) + lo));
        n02 = b2f(*(const u16*)((const char*)xs + p2 * 64 + ((hi ^ (p2 & 3)) << 4) + lo));
        n10 = b2f(*(const u16*)((const char*)xs + p3 * 64 + ((hi ^ (p3 & 3)) << 4) + lo));
        n11 = b2f(*(const u16*)((const char*)xs + p4 * 64 + ((hi ^ (p4 & 3)) << 4) + lo));
        n12 = b2f(*(const u16*)((const char*)xs + p5 * 64 + ((hi ^ (p5 & 3)) << 4) + lo));
        n20 = b2f(*(const u16*)((const char*)xs + p6 * 64 + ((hi ^ (p6 & 3)) << 4) + lo));
        n21 = b2f(*(const u16*)((const char*)xs + p7 * 64 + ((hi ^ (p7 & 3)) << 4) + lo));
        n22 = b2f(*(const u16*)((const char*)xs + p8 * 64 + ((hi ^ (p8 & 3)) << 4) + lo));
      }
      float v;
      if (br == 0) v = -(n00 + n01 + n10) + (n12 + n21 + n22);
      else if (br == 1) v = -3.f * n00 - 5.f * n01 - 5.f * n10 + 5.f * n12 + 5.f * n21 + 3.f * n22;
      else if (br == 2) v = 2.f * (n00 + n02 + n20 + n22) - 8.f * n11;
      else if (br == 3) v = 0.5f * (-n00 - n01 + n10 + n11);
      else v = 0.5f * n01 + n02 - 0.5f * n10 + 0.5f * n12 - n20 - 0.5f * n21;
      int gh = h0 - 1 + r, gw = w0 - 1 + c;
      bool valid = (gh >= 0 && gh < Hn && gw >= 0 && gw < Wn);
      float outv = valid ? (v - mean) : 0.f;
      *(u16*)((char*)bn + px * 64 + (((ic >> 3) ^ (px & 3)) << 4) + (ic & 7) * 2) = f2b(outv);
    }
    __syncthreads();

    const u16* Ab = A1n + ((size_t)b * 5 + br) * 9216;
    short8v af[9][2];
#pragma unroll
    for (int tp = 0; tp < 9; ++tp) {
      af[tp][0] = *(const short8v*)&Ab[((size_t)tp * 32 + ln) * 32 + q * 8];
      af[tp][1] = *(const short8v*)&Ab[((size_t)tp * 32 + 16 + ln) * 32 + q * 8];
    }
#pragma unroll
    for (int r4 = 0; r4 < 4; ++r4) {
      int rr = wv * 4 + r4;
#pragma unroll
      for (int dy = 0; dy < 3; ++dy) {
#pragma unroll
        for (int dx = 0; dx < 3; ++dx) {
          int px = (rr + dy) * 18 + ln + dx;
          short8v bf = *(const short8v*)((const char*)bn + px * 64 + ((q ^ (px & 3)) << 4));
          acc[r4][0] = __builtin_amdgcn_mfma_f32_16x16x32_bf16(af[dy * 3 + dx][0], bf, acc[r4][0], 0, 0, 0);
          acc[r4][1] = __builtin_amdgcn_mfma_f32_16x16x32_bf16(af[dy * 3 + dx][1], bf, acc[r4][1], 0, 0, 0);
        }
      }
    }
    __syncthreads();
  }

#pragma unroll
  for (int rp = 0; rp < 2; ++rp) {
#pragma unroll
    for (int g = 0; g < 2; ++g) {
      float m0 = fmaxf(acc[2 * rp][g][0], acc[2 * rp + 1][g][0]);
      float m1 = fmaxf(acc[2 * rp][g][1], acc[2 * rp + 1][g][1]);
      float m2 = fmaxf(acc[2 * rp][g][2], acc[2 * rp + 1][g][2]);
      float m3 = fmaxf(acc[2 * rp][g][3], acc[2 * rp + 1][g][3]);
      m0 = fmaxf(m0, __shfl_xor(m0, 1));
      m1 = fmaxf(m1, __shfl_xor(m1, 1));
      m2 = fmaxf(m2, __shfl_xor(m2, 1));
      m3 = fmaxf(m3, __shfl_xor(m3, 1));
      if (!(l & 1)) {
        int ph = (h0 >> 1) + wv * 2 + rp;
        int pw = (w0 >> 1) + (ln >> 1);
        uint2 pk;
        pk.x = (uint)f2b(m0 + b1[g * 16 + q * 4 + 0]) |
               ((uint)f2b(m1 + b1[g * 16 + q * 4 + 1]) << 16);
        pk.y = (uint)f2b(m2 + b1[g * 16 + q * 4 + 2]) |
               ((uint)f2b(m3 + b1[g * 16 + q * 4 + 3]) << 16);
        *(uint2*)&outb[(((size_t)b * 256 + ph) * 256 + pw) * 32 + g * 16 + q * 4] = pk;
      }
    }
  }
}

// ---------------------------------------------------------------------------
// Generic 3x3 MFMA conv, NHWC bf16 in. MODE 0: bf16 NHWC out.
// MODE 1: fp32 NCHW out * xorig (two-pass 16-oc LDS transpose epilogue).
// MODE 2: fused maxpool2x2 -> bf16 NHWC out at (H/2, W/2).
// ---------------------------------------------------------------------------
template <int CIN, int MODE>
__global__ void __launch_bounds__(256) k_conv_mfma(const u16* __restrict__ in,
                                                   const u16* __restrict__ Aw,
                                                   const float* __restrict__ bias,
                                                   u16* __restrict__ outb,
                                                   float* __restrict__ outf,
                                                   const float* __restrict__ xorig,
                                                   int H, int W) {
  constexpr int ICC = CIN / 32;
  __shared__ __align__(16) char smem[20736];
  u16* bs = (u16*)smem;
  int t = threadIdx.x;
  int l = t & 63, wv = t >> 6;
  int ln = l & 15, q = l >> 4;
  int bz = blockIdx.z;
  int h0 = blockIdx.y * 16, w0 = blockIdx.x * 16;

  float4v acc[4][2];
#pragma unroll
  for (int i = 0; i < 4; ++i) {
    acc[i][0] = (float4v){0.f, 0.f, 0.f, 0.f};
    acc[i][1] = (float4v){0.f, 0.f, 0.f, 0.f};
  }

  for (int icc = 0; icc < ICC; ++icc) {
    for (int u = t; u < 1296; u += 256) {
      int px = u >> 2, sq = u & 3;
      int ry = px / 18, rx = px - ry * 18;
      int gh = h0 - 1 + ry, gw = w0 - 1 + rx;
      uint4 v = {0, 0, 0, 0};
      if (gh >= 0 && gh < H && gw >= 0 && gw < W)
        v = *(const uint4*)&in[(((size_t)bz * H + gh) * W + gw) * CIN + icc * 32 + sq * 8];
      *(uint4*)((char*)bs + px * 64 + ((sq ^ (px & 3)) << 4)) = v;
    }
    short8v af[9][2];
#pragma unroll
    for (int tp = 0; tp < 9; ++tp) {
      af[tp][0] = *(const short8v*)&Aw[((size_t)(icc * 9 + tp) * 32 + ln) * 32 + q * 8];
      af[tp][1] = *(const short8v*)&Aw[((size_t)(icc * 9 + tp) * 32 + 16 + ln) * 32 + q * 8];
    }
    __syncthreads();
#pragma unroll
    for (int r4 = 0; r4 < 4; ++r4) {
      int r = wv * 4 + r4;
#pragma unroll
      for (int dy = 0; dy < 3; ++dy) {
#pragma unroll
        for (int dx = 0; dx < 3; ++dx) {
          int px = (r + dy) * 18 + ln + dx;
          short8v bf = *(const short8v*)((const char*)bs + px * 64 + ((q ^ (px & 3)) << 4));
          acc[r4][0] = __builtin_amdgcn_mfma_f32_16x16x32_bf16(af[dy * 3 + dx][0], bf, acc[r4][0], 0, 0, 0);
          acc[r4][1] = __builtin_amdgcn_mfma_f32_16x16x32_bf16(af[dy * 3 + dx][1], bf, acc[r4][1], 0, 0, 0);
        }
      }
    }
    if (ICC > 1) __syncthreads();
  }

  if (MODE == 0) {
#pragma unroll
    for (int r4 = 0; r4 < 4; ++r4) {
      int h = h0 + wv * 4 + r4;
      int wpix = w0 + ln;
#pragma unroll
      for (int g = 0; g < 2; ++g) {
        float v0 = acc[r4][g][0] + bias[g * 16 + q * 4 + 0];
        float v1 = acc[r4][g][1] + bias[g * 16 + q * 4 + 1];
        float v2 = acc[r4][g][2] + bias[g * 16 + q * 4 + 2];
        float v3 = acc[r4][g][3] + bias[g * 16 + q * 4 + 3];
        uint2 pk;
        pk.x = (uint)f2b(v0) | ((uint)f2b(v1) << 16);
        pk.y = (uint)f2b(v2) | ((uint)f2b(v3) << 16);
        *(uint2*)&outb[(((size_t)bz * H + h) * W + wpix) * 32 + g * 16 + q * 4] = pk;
      }
    }
  } else if (MODE == 2) {
    int Hp = H >> 1, Wp = W >> 1;
#pragma unroll
    for (int rp = 0; rp < 2; ++rp) {
#pragma unroll
      for (int g = 0; g < 2; ++g) {
        float m0 = fmaxf(acc[2 * rp][g][0], acc[2 * rp + 1][g][0]);
        float m1 = fmaxf(acc[2 * rp][g][1], acc[2 * rp + 1][g][1]);
        float m2 = fmaxf(acc[2 * rp][g][2], acc[2 * rp + 1][g][2]);
        float m3 = fmaxf(acc[2 * rp][g][3], acc[2 * rp + 1][g][3]);
        m0 = fmaxf(m0, __shfl_xor(m0, 1));
        m1 = fmaxf(m1, __shfl_xor(m1, 1));
        m2 = fmaxf(m2, __shfl_xor(m2, 1));
        m3 = fmaxf(m3, __shfl_xor(m3, 1));
        if (!(l & 1)) {
          int ph = (h0 >> 1) + wv * 2 + rp;
          int pw = (w0 >> 1) + (ln >> 1);
          uint2 pk;
          pk.x = (uint)f2b(m0 + bias[g * 16 + q * 4 + 0]) |
                 ((uint)f2b(m1 + bias[g * 16 + q * 4 + 1]) << 16);
          pk.y = (uint)f2b(m2 + bias[g * 16 + q * 4 + 2]) |
                 ((uint)f2b(m3 + bias[g * 16 + q * 4 + 3]) << 16);
          *(uint2*)&outb[(((size_t)bz * Hp + ph) * Wp + pw) * 32 + g * 16 + q * 4] = pk;
        }
      }
    }
  } else {
    // MODE 1: two-pass (16 oc each) LDS transpose, fused *xorig, fp32 NCHW
    float* os = (float*)smem;  // [ocl16][h16][w 20-stride] = 20480 B
#pragma unroll
    for (int g = 0; g < 2; ++g) {
      __syncthreads();
#pragma unroll
      for (int r4 = 0; r4 < 4; ++r4) {
        int hl = wv * 4 + r4;
#pragma unroll
        for (int i = 0; i < 4; ++i) {
          int ocl = q * 4 + i;
          os[(ocl * 16 + hl) * 20 + ln] = acc[r4][g][i] + bias[g * 16 + ocl];
        }
      }
      __syncthreads();
#pragma unroll
      for (int j = 0; j < 4; ++j) {
        int u = t + j * 256;  // 1024 float4 units
        int wq = u & 3, hh = (u >> 2) & 15, ocl = u >> 6;
        float4v v = *(const float4v*)&os[(ocl * 16 + hh) * 20 + wq * 4];
        size_t gidx = (((size_t)bz * 32 + g * 16 + ocl) * H + h0 + hh) * W + w0 + wq * 4;
        float4v xo = *(const float4v*)&xorig[gidx];
        v[0] *= xo[0]; v[1] *= xo[1]; v[2] *= xo[2]; v[3] *= xo[3];
        *(float4v*)&outf[gidx] = v;
      }
    }
  }
}

// ---------------------------------------------------------------------------
// deconv 2x2 s2 as 4 parity 1x1 GEMMs via MFMA.
// ---------------------------------------------------------------------------
__global__ void __launch_bounds__(256) k_deconv_mfma(const u16* __restrict__ in,
                                                     const u16* __restrict__ Aw,
                                                     const float* __restrict__ bias,
                                                     u16* __restrict__ out,
                                                     int Hi, int Wi) {
  int t = threadIdx.x;
  int l = t & 63, wv = t >> 6, ln = l & 15, q = l >> 4;
  int z = blockIdx.z, b = z >> 2, par = z & 3, p = par >> 1, qpar = par & 1;
  int h0 = blockIdx.y * 16, w0 = blockIdx.x * 16;
  int Ho = Hi * 2, Wo = Wi * 2;
  short8v af0 = *(const short8v*)&Aw[((size_t)par * 32 + ln) * 32 + q * 8];
  short8v af1 = *(const short8v*)&Aw[((size_t)par * 32 + 16 + ln) * 32 + q * 8];
#pragma unroll
  for (int r4 = 0; r4 < 4; ++r4) {
    int h = h0 + wv * 4 + r4;
    short8v bf = *(const short8v*)&in[(((size_t)b * Hi + h) * Wi + w0 + ln) * 32 + q * 8];
    float4v a0 = (float4v){0.f, 0.f, 0.f, 0.f};
    float4v a1 = (float4v){0.f, 0.f, 0.f, 0.f};
    a0 = __builtin_amdgcn_mfma_f32_16x16x32_bf16(af0, bf, a0, 0, 0, 0);
    a1 = __builtin_amdgcn_mfma_f32_16x16x32_bf16(af1, bf, a1, 0, 0, 0);
    int oh = 2 * h + p, ow = 2 * (w0 + ln) + qpar;
    size_t ob = (((size_t)b * Ho + oh) * Wo + ow) * 32;
    uint2 pk;
    pk.x = (uint)f2b(a0[0] + bias[q * 4 + 0]) | ((uint)f2b(a0[1] + bias[q * 4 + 1]) << 16);
    pk.y = (uint)f2b(a0[2] + bias[q * 4 + 2]) | ((uint)f2b(a0[3] + bias[q * 4 + 3]) << 16);
    *(uint2*)&out[ob + q * 4] = pk;
    pk.x = (uint)f2b(a1[0] + bias[16 + q * 4 + 0]) | ((uint)f2b(a1[1] + bias[16 + q * 4 + 1]) << 16);
    pk.y = (uint)f2b(a1[2] + bias[16 + q * 4 + 2]) | ((uint)f2b(a1[3] + bias[16 + q * 4 + 3]) << 16);
    *(uint2*)&out[ob + 16 + q * 4] = pk;
  }
}

// ---------------------------------------------------------------------------
extern "C" void kernel_launch(void* const* d_in, const int* in_sizes, int n_in,
                              void* d_out, int out_size, void* d_ws, size_t ws_size,
                              hipStream_t stream) {
  const float* x   = (const float*)d_in[0];
  const float* w1  = (const float*)d_in[1];
  const float* b1  = (const float*)d_in[2];
  const float* w2  = (const float*)d_in[3];
  const float* b2  = (const float*)d_in[4];
  const float* w3  = (const float*)d_in[5];
  const float* b3  = (const float*)d_in[6];
  const float* w4  = (const float*)d_in[7];
  const float* b4  = (const float*)d_in[8];
  const float* w5  = (const float*)d_in[9];
  const float* b5  = (const float*)d_in[10];
  const float* w6  = (const float*)d_in[11];
  const float* b6  = (const float*)d_in[12];
  const float* w7  = (const float*)d_in[13];
  const float* b7  = (const float*)d_in[14];
  const float* dw1 = (const float*)d_in[15];
  const float* db1 = (const float*)d_in[16];
  const float* dw2 = (const float*)d_in[17];
  const float* db2 = (const float*)d_in[18];
  const float* dw3 = (const float*)d_in[19];
  const float* db3 = (const float*)d_in[20];
  float* out = (float*)d_out;
  char* wsb = (char*)d_ws;

  u16* p1  = (u16*)(wsb + 0);               // 16,777,216
  u16* p2  = (u16*)(wsb + 16777216ull);     //  4,194,304
  u16* p3  = (u16*)(wsb + 20971520ull);     //  1,048,576
  u16* t4  = (u16*)(wsb + 22020096ull);     //  1,048,576
  u16* dc1 = (u16*)(wsb + 23068672ull);     //  4,194,304
  u16* t5  = (u16*)(wsb + 27262976ull);     //  4,194,304
  u16* dc2 = (u16*)(wsb + 31457280ull);     // 16,777,216
  u16* t6  = (u16*)(wsb + 48234496ull);     // 16,777,216
  u16* dc3 = (u16*)(wsb + 65011712ull);     // 67,108,864
  u16* A5c = (u16*)(wsb + 132120576ull);    //    204,800
  u16* A2  = (u16*)(wsb + 132325376ull);
  u16* A3  = (u16*)(wsb + 132343808ull);
  u16* A4  = (u16*)(wsb + 132362240ull);
  u16* A5  = (u16*)(wsb + 132380672ull);
  u16* A6  = (u16*)(wsb + 132399104ull);
  u16* A7  = (u16*)(wsb + 132417536ull);
  u16* Ad1 = (u16*)(wsb + 132435968ull);
  u16* Ad2 = (u16*)(wsb + 132444160ull);
  u16* Ad3 = (u16*)(wsb + 132452352ull);
  float* bias1all = (float*)(wsb + 132460544ull);
  float* partS    = (float*)(wsb + 132461056ull);
  float* partQ    = (float*)(wsb + 132788736ull);
  float* stats    = (float*)(wsb + 133116416ull);
  u16* A1n        = (u16*)(wsb + 133116576ull);  // 368,640

  k_prep_shared<<<264, 256, 0, stream>>>(w2, w3, w4, w5, w6, w7, dw1, dw2, dw3,
                                         A2, A3, A4, A5, A6, A7, Ad1, Ad2, Ad3);
  k_opstats<<<8192, 128, 0, stream>>>(x, partS, partQ);
  k_stats<<<20, 256, 0, stream>>>(partS, partQ, stats);
  k_prep_conv1<<<1121, 256, 0, stream>>>(w1, b1, stats, A5c, bias1all, A1n);

  // fused operator+conv1+pool: interior composed 5x5, perimeter exact
  k_conv5x5<<<dim3(32, 32, 4), 256, 0, stream>>>(x, A5c, bias1all, p1);
  k_conv1_edge<<<dim3(124, 4), 256, 0, stream>>>(x, A1n, b1, stats, p1);

  k_conv_mfma<32, 2><<<dim3(16, 16, 4), 256, 0, stream>>>(p1, A2, b2, p2, nullptr, nullptr, 256, 256);
  k_conv_mfma<32, 2><<<dim3(8, 8, 4), 256, 0, stream>>>(p2, A3, b3, p3, nullptr, nullptr, 128, 128);
  k_conv_mfma<32, 0><<<dim3(4, 4, 4), 256, 0, stream>>>(p3, A4, b4, t4, nullptr, nullptr, 64, 64);
  k_deconv_mfma<<<dim3(4, 4, 16), 256, 0, stream>>>(t4, Ad1, db1, dc1, 64, 64);
  k_conv_mfma<32, 0><<<dim3(8, 8, 4), 256, 0, stream>>>(dc1, A5, b5, t5, nullptr, nullptr, 128, 128);
  k_deconv_mfma<<<dim3(8, 8, 16), 256, 0, stream>>>(t5, Ad2, db2, dc2, 128, 128);
  k_conv_mfma<32, 0><<<dim3(16, 16, 4), 256, 0, stream>>>(dc2, A6, b6, t6, nullptr, nullptr, 256, 256);
  k_deconv_mfma<<<dim3(16, 16, 16), 256, 0, stream>>>(t6, Ad3, db3, dc3, 256, 256);
  k_conv_mfma<32, 1><<<dim3(32, 32, 4), 256, 0, stream>>>(dc3, A7, b7, nullptr, out, x, 512, 512);
}